// Round 6
// baseline (130.991 us; speedup 1.0000x reference)
//
#include <hip/hip_runtime.h>
#include <hip/hip_bf16.h>
#include <math.h>

#define BB 4
#define LL 1024
#define EE 1024
#define HH 16
#define DD 64
#define NCH 8
#define CHROWS 128   // LL / NCH
#define K2C 0.04508422002777998f   // log2(e)/32
#define BIASC 7.2134752044448f     // 160 * K2C : fixed softmax bias (|s|<=160 proven)

typedef __attribute__((ext_vector_type(8))) short short8;
typedef __attribute__((ext_vector_type(4))) float f32x4;
typedef __attribute__((ext_vector_type(16))) float f32x16;
typedef __attribute__((ext_vector_type(4))) int int4v;

static __device__ __forceinline__ unsigned short bfbits(float x) {
    __hip_bfloat16 h = __float2bfloat16(x);
    return *(unsigned short*)&h;
}

#define CVTPK(dst, lo_, hi_) \
    asm("v_cvt_pk_bf16_f32 %0, %1, %2" : "=v"(dst) : "v"(lo_), "v"(hi_))
#define PLSWAP(x_, y_) \
    asm("v_permlane32_swap_b32 %0, %1" : "+v"(x_), "+v"(y_))

// ---------------------------------------------------------------------------
// Kernel 1: grouped 3x3 conv over (l, d) per head, + bias -> bf16 qcb[bh][l][d]
// ---------------------------------------------------------------------------
__global__ __launch_bounds__(256) void conv_kernel(
    const float* __restrict__ query,
    const float* __restrict__ conv_w,
    const float* __restrict__ conv_b,
    __hip_bfloat16* __restrict__ qcb) {
    int tid = threadIdx.x;
    int d = tid & 63;
    int lr = tid >> 6;
    int tile = blockIdx.x;                 // B*H*(L/4)
    int l0 = (tile & (LL / 4 - 1)) << 2;
    int bh = tile >> 8;
    int h = bh & (HH - 1);
    int b = bh >> 4;
    int l = l0 + lr;

    const float* w = conv_w + h * 9;
    float acc = conv_b[h];
    const float* qin = query + ((size_t)b * LL) * EE + h * DD;
    #pragma unroll
    for (int i = 0; i < 3; ++i) {
        int li = l + i - 1;
        if (li < 0 || li >= LL) continue;
        #pragma unroll
        for (int j = 0; j < 3; ++j) {
            int dj = d + j - 1;
            if (dj < 0 || dj >= DD) continue;
            acc += w[i * 3 + j] * qin[(size_t)li * EE + dj];
        }
    }
    qcb[((size_t)bh * LL + l) * DD + d] = __float2bfloat16(acc);
}

// ---------------------------------------------------------------------------
// Kernel 2a: per-chunk partial (max, sumexp) for keys column-softmax.
// Also (h==0 blocks) precompute maskf[b][l] = (pad&cau) ? -1e20 : 0.
// ---------------------------------------------------------------------------
__global__ __launch_bounds__(256) void ksm_partial_kernel(
    const float* __restrict__ keys,
    const int* __restrict__ bern,
    const int* __restrict__ pad,
    const int* __restrict__ cau,
    float* __restrict__ pmax,
    float* __restrict__ psum,
    float* __restrict__ maskf) {
    __shared__ float sm[4][64], ss[4][64];
    int tid = threadIdx.x;
    int d = tid & 63;
    int seg = tid >> 6;
    int blk = blockIdx.x;
    int ch = blk & (NCH - 1);
    int bh = blk >> 3;
    int h = bh & (HH - 1);
    int b = bh >> 4;
    int r0 = ch * CHROWS + seg * 32;

    if (h == 0 && tid < CHROWS) {
        int l = ch * CHROWS + tid;
        maskf[b * LL + l] = ((pad[b * LL + l] != 0) & (cau[b * LL + l] != 0)) ? -1e20f : 0.f;
    }

    const float* kin = keys + ((size_t)b * LL + r0) * EE + h * DD + d;
    const int* bm = bern + (size_t)bh * LL + r0;

    float v[32];
    #pragma unroll
    for (int i = 0; i < 32; ++i) v[i] = kin[(size_t)i * EE];
    float m = -INFINITY;
    #pragma unroll
    for (int i = 0; i < 32; ++i)
        if (bm[i]) m = fmaxf(m, v[i]);
    float s = 0.f;
    #pragma unroll
    for (int i = 0; i < 32; ++i)
        if (bm[i]) s += __expf(v[i] - m);

    sm[seg][d] = m;
    ss[seg][d] = s;
    __syncthreads();
    if (seg == 0) {
        float M = sm[0][d];
        #pragma unroll
        for (int t = 1; t < 4; ++t) M = fmaxf(M, sm[t][d]);
        float S = 0.f;
        if (M > -INFINITY) {
            #pragma unroll
            for (int t = 0; t < 4; ++t)
                if (sm[t][d] > -INFINITY) S += ss[t][d] * __expf(sm[t][d] - M);
        }
        pmax[(size_t)blk * 64 + d] = M;
        psum[(size_t)blk * 64 + d] = S;
    }
}

// ---------------------------------------------------------------------------
// Kernel 2b: combine chunk partials; normalize chunk; write bf16 ksb.
// ---------------------------------------------------------------------------
__global__ __launch_bounds__(256) void ksm_final_kernel(
    const float* __restrict__ keys,
    const int* __restrict__ bern,
    const float* __restrict__ pmax,
    const float* __restrict__ psum,
    __hip_bfloat16* __restrict__ ksb) {
    int tid = threadIdx.x;
    int d = tid & 63;
    int seg = tid >> 6;
    int blk = blockIdx.x;
    int ch = blk & (NCH - 1);
    int bh = blk >> 3;
    int h = bh & (HH - 1);
    int b = bh >> 4;
    int r0 = ch * CHROWS + seg * 32;

    const float* pm = pmax + (size_t)bh * NCH * 64;
    const float* ps = psum + (size_t)bh * NCH * 64;
    float M = -INFINITY;
    #pragma unroll
    for (int c = 0; c < NCH; ++c) M = fmaxf(M, pm[c * 64 + d]);
    float S = 0.f;
    #pragma unroll
    for (int c = 0; c < NCH; ++c) {
        float mi = pm[c * 64 + d];
        if (mi > -INFINITY) S += ps[c * 64 + d] * __expf(mi - M);
    }
    float inv = 1.f / S;

    const float* kin = keys + ((size_t)b * LL + r0) * EE + h * DD + d;
    const int* bm = bern + (size_t)bh * LL + r0;
    __hip_bfloat16* kout = ksb + ((size_t)bh * LL + r0) * DD + d;
    #pragma unroll
    for (int i = 0; i < 32; ++i) {
        float val = bm[i] ? __expf(kin[(size_t)i * EE] - M) * inv : 0.f;
        kout[(size_t)i * DD] = __float2bfloat16(val);
    }
}

// ---------------------------------------------------------------------------
// Kernel 3: per-head value linear -> TRANSPOSED bf16 vt[bh][d][l]
// ---------------------------------------------------------------------------
__global__ __launch_bounds__(256) void vlin_kernel(
    const float* __restrict__ values,
    const float* __restrict__ Wv,
    __hip_bfloat16* __restrict__ vt) {
    __shared__ float WvS[64][65];
    __shared__ float vs[64][68];
    int tid = threadIdx.x;
    int tile = blockIdx.x;                 // B*H*(L/64) = 1024
    int lt = tile & 15;
    int bh = tile >> 4;
    int h = bh & (HH - 1);
    int b = bh >> 4;
    int l0 = lt * 64;

    for (int idx = tid; idx < 64 * 64; idx += 256)
        WvS[idx >> 6][idx & 63] = Wv[idx];
    const float* vin = values + ((size_t)b * LL + l0) * EE + h * DD;
    for (int idx = tid; idx < 1024; idx += 256) {
        int r = idx >> 4;
        int c4 = (idx & 15) << 2;
        *(float4*)&vs[r][c4] = *(const float4*)&vin[(size_t)r * EE + c4];
    }
    __syncthreads();

    int d = tid & 63;
    int r0 = (tid >> 6) * 16;
    float acc[16];
    #pragma unroll
    for (int r = 0; r < 16; ++r) acc[r] = 0.f;
    for (int k = 0; k < 64; ++k) {
        float wv = WvS[d][k];
        #pragma unroll
        for (int r = 0; r < 16; ++r) acc[r] += vs[r0 + r][k] * wv;
    }
    union { unsigned short us[16]; uint4 v[2]; } pk;
    #pragma unroll
    for (int r = 0; r < 16; ++r) pk.us[r] = bfbits(acc[r]);
    __hip_bfloat16* vo = vt + ((size_t)bh * DD + d) * LL + l0 + r0;
    *(uint4*)&vo[0] = pk.v[0];
    *(uint4*)&vo[8] = pk.v[1];
}

// ---------------------------------------------------------------------------
// Kernel 4: swapped-QK^T MFMA flash attention, NO LDS STAGING (KV is L2-hot:
// 256KB per bh, 8 bh per XCD's 4MB L2 via swizzle). No barriers in the loop;
// fixed-bias softmax (no row max, no rescale): scale cancels in O/sum(p).
// 4 waves x 32 q-rows = 128 q/block; 512 blocks.
// ---------------------------------------------------------------------------
__global__ __launch_bounds__(256) void attn_mfma_kernel(
    const __hip_bfloat16* __restrict__ qcb,
    const __hip_bfloat16* __restrict__ ksb,
    const __hip_bfloat16* __restrict__ vtb,
    const float* __restrict__ maskf,
    float* __restrict__ out) {
    __shared__ __align__(16) float OutS[4][32 * 36];

    int tid = threadIdx.x;
    int lane = tid & 63;
    int w = tid >> 6;                  // 4 waves
    int q5 = lane & 31;
    int hi = lane >> 5;

    // XCD swizzle: 512 blocks; consecutive swz on one XCD -> 8 bh per XCD L2
    int bid = blockIdx.x;
    int swz = (bid & 7) * 64 + (bid >> 3);
    int bh = swz >> 3;
    int qb = swz & 7;
    int b = bh >> 4;
    int h = bh & 15;
    int q0w = qb * 128 + w * 32;

    const short* kbase = (const short*)ksb + (size_t)bh * LL * DD;  // [l][d]
    const short* vbase = (const short*)vtb + (size_t)bh * DD * LL;  // [d][l]
    const float* mb = maskf + b * LL;

    // Q fragments (B-operand): Qf[i] = Q[q5][16i + 8hi .. +8]
    short8 Qf[4];
    {
        const short* qrow = (const short*)qcb + ((size_t)bh * LL + q0w + q5) * DD + 8 * hi;
        #pragma unroll
        for (int i = 0; i < 4; ++i)
            Qf[i] = *(const short8*)(qrow + 16 * i);
    }

    f32x16 O0, O1;
    #pragma unroll
    for (int e = 0; e < 16; ++e) { O0[e] = 0.f; O1[e] = 0.f; }
    float lrun = 0.f;

    for (int kt = 0; kt < 16; ++kt) {
        int k0 = kt * 64;

        // K fragments straight from global (L2-hot), contiguous 16B per lane
        short8 Ka0[4], Ka1[4];
        #pragma unroll
        for (int i = 0; i < 4; ++i) {
            Ka0[i] = *(const short8*)&kbase[(size_t)(k0 + q5) * DD + 16 * i + 8 * hi];
            Ka1[i] = *(const short8*)&kbase[(size_t)(k0 + 32 + q5) * DD + 16 * i + 8 * hi];
        }

        f32x16 S0, S1;
        #pragma unroll
        for (int e = 0; e < 16; ++e) { S0[e] = 0.f; S1[e] = 0.f; }
        __builtin_amdgcn_s_setprio(1);
        #pragma unroll
        for (int i = 0; i < 4; ++i) {
            S0 = __builtin_amdgcn_mfma_f32_32x32x16_bf16(Ka0[i], Qf[i], S0, 0, 0, 0);
            S1 = __builtin_amdgcn_mfma_f32_32x32x16_bf16(Ka1[i], Qf[i], S1, 0, 0, 0);
        }
        __builtin_amdgcn_s_setprio(0);

        // V fragments (needed after softmax; issue now to hide L2 latency)
        short8 Va0[4], Va1[4];
        #pragma unroll
        for (int i = 0; i < 4; ++i) {
            Va0[i] = *(const short8*)&vbase[(size_t)q5 * LL + k0 + 16 * i + 8 * hi];
            Va1[i] = *(const short8*)&vbase[(size_t)(32 + q5) * LL + k0 + 16 * i + 8 * hi];
        }
        // additive mask, float4 per 4 consecutive kv rows of this lane's slots
        float4 mk0[4], mk1[4];
        #pragma unroll
        for (int a = 0; a < 4; ++a) {
            mk0[a] = *(const float4*)&mb[k0 + 8 * a + 4 * hi];
            mk1[a] = *(const float4*)&mb[k0 + 32 + 8 * a + 4 * hi];
        }

        // fixed-bias softmax: pv = exp2((s + mask)*K2C - BIASC); masked -> 0
        float pv[32];
        #pragma unroll
        for (int a = 0; a < 4; ++a) {
            #pragma unroll
            for (int j = 0; j < 4; ++j) {
                float s0 = S0[4 * a + j] + mk0[a][j];
                float s1 = S1[4 * a + j] + mk1[a][j];
                pv[4 * a + j]      = exp2f(__builtin_fmaf(s0, K2C, -BIASC));
                pv[16 + 4 * a + j] = exp2f(__builtin_fmaf(s1, K2C, -BIASC));
            }
        }

        float t16[16];
        #pragma unroll
        for (int r = 0; r < 16; ++r) t16[r] = pv[r] + pv[r + 16];
        float t8[8];
        #pragma unroll
        for (int r = 0; r < 8; ++r) t8[r] = t16[r] + t16[r + 8];
        float rs = ((t8[0] + t8[1]) + (t8[2] + t8[3])) + ((t8[4] + t8[5]) + (t8[6] + t8[7]));
        rs += __shfl_xor(rs, 32, 64);
        lrun += rs;

        // pack P -> B-fragments via cvt_pk + permlane32_swap
        union PW { int4v i4; short8 s8; } pa[4];
        #pragma unroll
        for (int st = 0; st < 2; ++st) {
            int c0, d0, c1, d1, c2, d2, c3, d3;
            CVTPK(c0, pv[16 * st + 0], pv[16 * st + 1]);
            CVTPK(d0, pv[16 * st + 4], pv[16 * st + 5]);
            PLSWAP(c0, d0);
            CVTPK(c1, pv[16 * st + 2], pv[16 * st + 3]);
            CVTPK(d1, pv[16 * st + 6], pv[16 * st + 7]);
            PLSWAP(c1, d1);
            pa[2 * st].i4 = (int4v){c0, c1, d0, d1};
            CVTPK(c2, pv[16 * st + 8], pv[16 * st + 9]);
            CVTPK(d2, pv[16 * st + 12], pv[16 * st + 13]);
            PLSWAP(c2, d2);
            CVTPK(c3, pv[16 * st + 10], pv[16 * st + 11]);
            CVTPK(d3, pv[16 * st + 14], pv[16 * st + 15]);
            PLSWAP(c3, d3);
            pa[2 * st + 1].i4 = (int4v){c2, c3, d2, d3};
        }

        __builtin_amdgcn_s_setprio(1);
        #pragma unroll
        for (int ks = 0; ks < 4; ++ks) {
            O0 = __builtin_amdgcn_mfma_f32_32x32x16_bf16(Va0[ks], pa[ks].s8, O0, 0, 0, 0);
            O1 = __builtin_amdgcn_mfma_f32_32x32x16_bf16(Va1[ks], pa[ks].s8, O1, 0, 0, 0);
        }
        __builtin_amdgcn_s_setprio(0);
    }

    // epilogue: per-wave transpose O^T -> row-major via private LDS region
    float invl = 1.f / lrun;
    float* oreg = OutS[w];
    int orow = lane >> 1;
    int ocol = (lane & 1) * 16;

    #pragma unroll
    for (int r = 0; r < 16; ++r) {
        int dl = (r & 3) + 8 * (r >> 2) + 4 * hi;
        oreg[q5 * 36 + dl] = O0[r];
    }
    if (hi == 0) oreg[q5 * 36 + 32] = invl;
    asm volatile("" ::: "memory");
    {
        float iv = oreg[orow * 36 + 32];
        float* gout = out + ((size_t)b * LL + q0w + orow) * EE + h * DD + ocol;
        #pragma unroll
        for (int c = 0; c < 4; ++c) {
            float4 vv = *(float4*)&oreg[orow * 36 + ocol + 4 * c];
            vv.x *= iv; vv.y *= iv; vv.z *= iv; vv.w *= iv;
            *(float4*)&gout[4 * c] = vv;
        }
    }
    asm volatile("" ::: "memory");
    #pragma unroll
    for (int r = 0; r < 16; ++r) {
        int dl = (r & 3) + 8 * (r >> 2) + 4 * hi;
        oreg[q5 * 36 + dl] = O1[r];
    }
    asm volatile("" ::: "memory");
    {
        float iv = oreg[orow * 36 + 32];
        float* gout = out + ((size_t)b * LL + q0w + orow) * EE + h * DD + 32 + ocol;
        #pragma unroll
        for (int c = 0; c < 4; ++c) {
            float4 vv = *(float4*)&oreg[orow * 36 + ocol + 4 * c];
            vv.x *= iv; vv.y *= iv; vv.z *= iv; vv.w *= iv;
            *(float4*)&gout[4 * c] = vv;
        }
    }
}

extern "C" void kernel_launch(void* const* d_in, const int* in_sizes, int n_in,
                              void* d_out, int out_size, void* d_ws, size_t ws_size,
                              hipStream_t stream) {
    const float* query = (const float*)d_in[0];
    const float* keys  = (const float*)d_in[1];
    const float* values = (const float*)d_in[2];
    const int* pad  = (const int*)d_in[3];
    const int* cau  = (const int*)d_in[4];
    const int* bern = (const int*)d_in[5];
    const float* conv_w = (const float*)d_in[6];
    const float* conv_b = (const float*)d_in[7];
    const float* Wv = (const float*)d_in[8];
    float* outp = (float*)d_out;

    const size_t per = (size_t)BB * HH * LL * DD;
    __hip_bfloat16* qcb = (__hip_bfloat16*)d_ws;
    __hip_bfloat16* ksb = qcb + per;
    __hip_bfloat16* vtb = ksb + per;
    float* pmax = (float*)(vtb + per);
    float* psum = pmax + (size_t)BB * HH * NCH * 64;
    float* maskf = psum + (size_t)BB * HH * NCH * 64;

    conv_kernel<<<BB * HH * (LL / 4), 256, 0, stream>>>(query, conv_w, conv_b, qcb);
    ksm_partial_kernel<<<BB * HH * NCH, 256, 0, stream>>>(keys, bern, pad, cau, pmax, psum, maskf);
    ksm_final_kernel<<<BB * HH * NCH, 256, 0, stream>>>(keys, bern, pmax, psum, ksb);
    vlin_kernel<<<BB * HH * (LL / 64), 256, 0, stream>>>(values, Wv, vtb);
    attn_mfma_kernel<<<BB * HH * 8, 256, 0, stream>>>(qcb, ksb, vtb, maskf, outp);
}

// Round 7
// 112.748 us; speedup vs baseline: 1.1618x; 1.1618x over previous
//
#include <hip/hip_runtime.h>
#include <hip/hip_bf16.h>
#include <math.h>

#define BB 4
#define LL 1024
#define EE 1024
#define HH 16
#define DD 64
#define NCH 8
#define CHROWS 128   // LL / NCH
#define K2C 0.04508422002777998f   // log2(e)/32
#define BIASC 7.2134752044448f     // 160 * K2C : fixed softmax bias

typedef __attribute__((ext_vector_type(8))) short short8;
typedef __attribute__((ext_vector_type(4))) float f32x4;
typedef __attribute__((ext_vector_type(16))) float f32x16;
typedef __attribute__((ext_vector_type(4))) int int4v;

static __device__ __forceinline__ unsigned short bfbits(float x) {
    __hip_bfloat16 h = __float2bfloat16(x);
    return *(unsigned short*)&h;
}

#define CVTPK(dst, lo_, hi_) \
    asm("v_cvt_pk_bf16_f32 %0, %1, %2" : "=v"(dst) : "v"(lo_), "v"(hi_))
#define PLSWAP(x_, y_) \
    asm("v_permlane32_swap_b32 %0, %1" : "+v"(x_), "+v"(y_))

// ---------------------------------------------------------------------------
// Kernel 1: grouped 3x3 conv over (l, d) per head, + bias -> bf16 qcb[bh][l][d]
// ---------------------------------------------------------------------------
__global__ __launch_bounds__(256) void conv_kernel(
    const float* __restrict__ query,
    const float* __restrict__ conv_w,
    const float* __restrict__ conv_b,
    __hip_bfloat16* __restrict__ qcb) {
    int tid = threadIdx.x;
    int d = tid & 63;
    int lr = tid >> 6;
    int tile = blockIdx.x;                 // B*H*(L/4)
    int l0 = (tile & (LL / 4 - 1)) << 2;
    int bh = tile >> 8;
    int h = bh & (HH - 1);
    int b = bh >> 4;
    int l = l0 + lr;

    const float* w = conv_w + h * 9;
    float acc = conv_b[h];
    const float* qin = query + ((size_t)b * LL) * EE + h * DD;
    #pragma unroll
    for (int i = 0; i < 3; ++i) {
        int li = l + i - 1;
        if (li < 0 || li >= LL) continue;
        #pragma unroll
        for (int j = 0; j < 3; ++j) {
            int dj = d + j - 1;
            if (dj < 0 || dj >= DD) continue;
            acc += w[i * 3 + j] * qin[(size_t)li * EE + dj];
        }
    }
    qcb[((size_t)bh * LL + l) * DD + d] = __float2bfloat16(acc);
}

// ---------------------------------------------------------------------------
// Kernel 2a: per-chunk partial (max, sumexp) for keys column-softmax.
// Also (h==0 blocks) precompute maskf[b][l] = (pad&cau) ? -1e20 : 0.
// ---------------------------------------------------------------------------
__global__ __launch_bounds__(256) void ksm_partial_kernel(
    const float* __restrict__ keys,
    const int* __restrict__ bern,
    const int* __restrict__ pad,
    const int* __restrict__ cau,
    float* __restrict__ pmax,
    float* __restrict__ psum,
    float* __restrict__ maskf) {
    __shared__ float sm[4][64], ss[4][64];
    int tid = threadIdx.x;
    int d = tid & 63;
    int seg = tid >> 6;
    int blk = blockIdx.x;
    int ch = blk & (NCH - 1);
    int bh = blk >> 3;
    int h = bh & (HH - 1);
    int b = bh >> 4;
    int r0 = ch * CHROWS + seg * 32;

    if (h == 0 && tid < CHROWS) {
        int l = ch * CHROWS + tid;
        maskf[b * LL + l] = ((pad[b * LL + l] != 0) & (cau[b * LL + l] != 0)) ? -1e20f : 0.f;
    }

    const float* kin = keys + ((size_t)b * LL + r0) * EE + h * DD + d;
    const int* bm = bern + (size_t)bh * LL + r0;

    float v[32];
    #pragma unroll
    for (int i = 0; i < 32; ++i) v[i] = kin[(size_t)i * EE];
    float m = -INFINITY;
    #pragma unroll
    for (int i = 0; i < 32; ++i)
        if (bm[i]) m = fmaxf(m, v[i]);
    float s = 0.f;
    #pragma unroll
    for (int i = 0; i < 32; ++i)
        if (bm[i]) s += __expf(v[i] - m);

    sm[seg][d] = m;
    ss[seg][d] = s;
    __syncthreads();
    if (seg == 0) {
        float M = sm[0][d];
        #pragma unroll
        for (int t = 1; t < 4; ++t) M = fmaxf(M, sm[t][d]);
        float S = 0.f;
        if (M > -INFINITY) {
            #pragma unroll
            for (int t = 0; t < 4; ++t)
                if (sm[t][d] > -INFINITY) S += ss[t][d] * __expf(sm[t][d] - M);
        }
        pmax[(size_t)blk * 64 + d] = M;
        psum[(size_t)blk * 64 + d] = S;
    }
}

// ---------------------------------------------------------------------------
// Kernel 2b: combine chunk partials; normalize chunk; write bf16 ksb.
// ---------------------------------------------------------------------------
__global__ __launch_bounds__(256) void ksm_final_kernel(
    const float* __restrict__ keys,
    const int* __restrict__ bern,
    const float* __restrict__ pmax,
    const float* __restrict__ psum,
    __hip_bfloat16* __restrict__ ksb) {
    int tid = threadIdx.x;
    int d = tid & 63;
    int seg = tid >> 6;
    int blk = blockIdx.x;
    int ch = blk & (NCH - 1);
    int bh = blk >> 3;
    int h = bh & (HH - 1);
    int b = bh >> 4;
    int r0 = ch * CHROWS + seg * 32;

    const float* pm = pmax + (size_t)bh * NCH * 64;
    const float* ps = psum + (size_t)bh * NCH * 64;
    float M = -INFINITY;
    #pragma unroll
    for (int c = 0; c < NCH; ++c) M = fmaxf(M, pm[c * 64 + d]);
    float S = 0.f;
    #pragma unroll
    for (int c = 0; c < NCH; ++c) {
        float mi = pm[c * 64 + d];
        if (mi > -INFINITY) S += ps[c * 64 + d] * __expf(mi - M);
    }
    float inv = 1.f / S;

    const float* kin = keys + ((size_t)b * LL + r0) * EE + h * DD + d;
    const int* bm = bern + (size_t)bh * LL + r0;
    __hip_bfloat16* kout = ksb + ((size_t)bh * LL + r0) * DD + d;
    #pragma unroll
    for (int i = 0; i < 32; ++i) {
        float val = bm[i] ? __expf(kin[(size_t)i * EE] - M) * inv : 0.f;
        kout[(size_t)i * DD] = __float2bfloat16(val);
    }
}

// ---------------------------------------------------------------------------
// Kernel 3: per-head value linear -> TRANSPOSED bf16 vt[bh][d][l]
// ---------------------------------------------------------------------------
__global__ __launch_bounds__(256) void vlin_kernel(
    const float* __restrict__ values,
    const float* __restrict__ Wv,
    __hip_bfloat16* __restrict__ vt) {
    __shared__ float WvS[64][65];
    __shared__ float vs[64][68];
    int tid = threadIdx.x;
    int tile = blockIdx.x;                 // B*H*(L/64) = 1024
    int lt = tile & 15;
    int bh = tile >> 4;
    int h = bh & (HH - 1);
    int b = bh >> 4;
    int l0 = lt * 64;

    for (int idx = tid; idx < 64 * 64; idx += 256)
        WvS[idx >> 6][idx & 63] = Wv[idx];
    const float* vin = values + ((size_t)b * LL + l0) * EE + h * DD;
    for (int idx = tid; idx < 1024; idx += 256) {
        int r = idx >> 4;
        int c4 = (idx & 15) << 2;
        *(float4*)&vs[r][c4] = *(const float4*)&vin[(size_t)r * EE + c4];
    }
    __syncthreads();

    int d = tid & 63;
    int r0 = (tid >> 6) * 16;
    float acc[16];
    #pragma unroll
    for (int r = 0; r < 16; ++r) acc[r] = 0.f;
    for (int k = 0; k < 64; ++k) {
        float wv = WvS[d][k];
        #pragma unroll
        for (int r = 0; r < 16; ++r) acc[r] += vs[r0 + r][k] * wv;
    }
    union { unsigned short us[16]; uint4 v[2]; } pk;
    #pragma unroll
    for (int r = 0; r < 16; ++r) pk.us[r] = bfbits(acc[r]);
    __hip_bfloat16* vo = vt + ((size_t)bh * DD + d) * LL + l0 + r0;
    *(uint4*)&vo[0] = pk.v[0];
    *(uint4*)&vo[8] = pk.v[1];
}

// ---------------------------------------------------------------------------
// Kernel 4: swapped-QK^T MFMA flash attention, KV-SPLIT across wave groups.
// 512 threads = 8 waves: group A (w0-3) even KV tiles, group B (w4-7) odd.
// Fixed-bias softmax makes partials addable. 4 LDS tile slots shared by all.
// Grid 512 blocks -> 4096 waves = 4 waves/SIMD.
// ---------------------------------------------------------------------------
__global__ __launch_bounds__(512, 4) void attn_mfma_kernel(
    const __hip_bfloat16* __restrict__ qcb,
    const __hip_bfloat16* __restrict__ ksb,
    const __hip_bfloat16* __restrict__ vtb,
    const float* __restrict__ maskf,
    float* __restrict__ out) {
    __shared__ __align__(16) char SMEM[65536];
    short* KsS = (short*)SMEM;                // [4][4096] tile slots (K)
    short* VtS = (short*)(SMEM + 32768);      // [4][4096] tile slots (V^T)

    int tid = threadIdx.x;
    int lane = tid & 63;
    int w = tid >> 6;          // 0..7
    int grp = w >> 2;          // 0: even tiles, 1: odd tiles
    int wq = w & 3;            // q-chunk within block
    int q5 = lane & 31;
    int hi = lane >> 5;

    // XCD swizzle: 512 blocks; 64 consecutive swz per XCD -> 8 bh in its L2
    int bid = blockIdx.x;
    int swz = (bid & 7) * 64 + (bid >> 3);
    int bh = swz >> 3;
    int qb = swz & 7;
    int b = bh >> 4;
    int h = bh & 15;
    int q0w = qb * 128 + wq * 32;

    const short* kbase = (const short*)ksb + (size_t)bh * LL * DD;  // [l][d]
    const short* vbase = (const short*)vtb + (size_t)bh * DD * LL;  // [d][l]
    const float* mb = maskf + b * LL;

    // staging geometry: 512 threads = 64 rows x 8 chunks of 8 bf16 per tile
    int srow = tid >> 3;
    int sch = tid & 7;
    int ssw = (sch ^ (srow & 7)) << 3;
    const short* kg = kbase + (size_t)srow * DD + ssw;
    const short* vg = vbase + (size_t)srow * LL + ssw;

    // Q fragments (B-operand)
    short8 Qf[4];
    {
        const short* qrow = (const short*)qcb + ((size_t)bh * LL + q0w + q5) * DD + 8 * hi;
        #pragma unroll
        for (int i = 0; i < 4; ++i)
            Qf[i] = *(const short8*)(qrow + 16 * i);
    }

    // prologue: tiles 0,1 -> slots 0,1
    #pragma unroll
    for (int t = 0; t < 2; ++t) {
        __builtin_amdgcn_global_load_lds(
            (const __attribute__((address_space(1))) void*)(kg + (size_t)t * 64 * DD),
            (__attribute__((address_space(3))) void*)&KsS[t * 4096 + w * 512], 16, 0, 0);
        __builtin_amdgcn_global_load_lds(
            (const __attribute__((address_space(1))) void*)(vg + t * 64),
            (__attribute__((address_space(3))) void*)&VtS[t * 4096 + w * 512], 16, 0, 0);
    }
    __syncthreads();

    f32x16 O0, O1;
    #pragma unroll
    for (int e = 0; e < 16; ++e) { O0[e] = 0.f; O1[e] = 0.f; }
    float lrun = 0.f;

    for (int j = 0; j < 8; ++j) {
        // prefetch tiles 2j+2, 2j+3 into the slots consumed at step j-1
        if (j < 7) {
            #pragma unroll
            for (int t = 0; t < 2; ++t) {
                int tl = 2 * j + 2 + t;
                int sl = tl & 3;
                __builtin_amdgcn_global_load_lds(
                    (const __attribute__((address_space(1))) void*)(kg + (size_t)tl * 64 * DD),
                    (__attribute__((address_space(3))) void*)&KsS[sl * 4096 + w * 512], 16, 0, 0);
                __builtin_amdgcn_global_load_lds(
                    (const __attribute__((address_space(1))) void*)(vg + tl * 64),
                    (__attribute__((address_space(3))) void*)&VtS[sl * 4096 + w * 512], 16, 0, 0);
            }
        }

        int slot = (2 * j + grp) & 3;
        int k0 = j * 128 + 64 * grp;
        const short* Kb = &KsS[slot * 4096];
        const short* Vb = &VtS[slot * 4096];
        int rsw = q5 & 7;

        // K fragments from LDS (XOR-swizzled)
        short8 Ka0[4], Ka1[4];
        #pragma unroll
        for (int i = 0; i < 4; ++i) {
            int off = ((2 * i + hi) ^ rsw) << 3;
            Ka0[i] = *(const short8*)&Kb[q5 * 64 + off];
            Ka1[i] = *(const short8*)&Kb[(32 + q5) * 64 + off];
        }

        f32x16 S0, S1;
        #pragma unroll
        for (int e = 0; e < 16; ++e) { S0[e] = 0.f; S1[e] = 0.f; }
        __builtin_amdgcn_s_setprio(1);
        #pragma unroll
        for (int i = 0; i < 4; ++i) {
            S0 = __builtin_amdgcn_mfma_f32_32x32x16_bf16(Ka0[i], Qf[i], S0, 0, 0, 0);
            S1 = __builtin_amdgcn_mfma_f32_32x32x16_bf16(Ka1[i], Qf[i], S1, 0, 0, 0);
        }
        __builtin_amdgcn_s_setprio(0);

        // additive mask from global (L2-hot, 256B/tile/wave)
        float4 mk0[4], mk1[4];
        #pragma unroll
        for (int a = 0; a < 4; ++a) {
            mk0[a] = *(const float4*)&mb[k0 + 8 * a + 4 * hi];
            mk1[a] = *(const float4*)&mb[k0 + 32 + 8 * a + 4 * hi];
        }

        // fixed-bias softmax: pv = exp2((s + mask)*K2C - BIASC)
        float pv[32];
        #pragma unroll
        for (int a = 0; a < 4; ++a) {
            #pragma unroll
            for (int jj = 0; jj < 4; ++jj) {
                float s0 = S0[4 * a + jj] + mk0[a][jj];
                float s1 = S1[4 * a + jj] + mk1[a][jj];
                pv[4 * a + jj]      = exp2f(__builtin_fmaf(s0, K2C, -BIASC));
                pv[16 + 4 * a + jj] = exp2f(__builtin_fmaf(s1, K2C, -BIASC));
            }
        }

        float t16[16];
        #pragma unroll
        for (int r = 0; r < 16; ++r) t16[r] = pv[r] + pv[r + 16];
        float t8[8];
        #pragma unroll
        for (int r = 0; r < 8; ++r) t8[r] = t16[r] + t16[r + 8];
        float rs = ((t8[0] + t8[1]) + (t8[2] + t8[3])) + ((t8[4] + t8[5]) + (t8[6] + t8[7]));
        rs += __shfl_xor(rs, 32, 64);
        lrun += rs;

        // pack P -> B-fragments via cvt_pk + permlane32_swap
        union PW { int4v i4; short8 s8; } pa[4];
        #pragma unroll
        for (int st = 0; st < 2; ++st) {
            int c0, d0, c1, d1, c2, d2, c3, d3;
            CVTPK(c0, pv[16 * st + 0], pv[16 * st + 1]);
            CVTPK(d0, pv[16 * st + 4], pv[16 * st + 5]);
            PLSWAP(c0, d0);
            CVTPK(c1, pv[16 * st + 2], pv[16 * st + 3]);
            CVTPK(d1, pv[16 * st + 6], pv[16 * st + 7]);
            PLSWAP(c1, d1);
            pa[2 * st].i4 = (int4v){c0, c1, d0, d1};
            CVTPK(c2, pv[16 * st + 8], pv[16 * st + 9]);
            CVTPK(d2, pv[16 * st + 12], pv[16 * st + 13]);
            PLSWAP(c2, d2);
            CVTPK(c3, pv[16 * st + 10], pv[16 * st + 11]);
            CVTPK(d3, pv[16 * st + 14], pv[16 * st + 15]);
            PLSWAP(c3, d3);
            pa[2 * st + 1].i4 = (int4v){c2, c3, d2, d3};
        }

        // V fragments from LDS + PV MFMAs
        __builtin_amdgcn_s_setprio(1);
        #pragma unroll
        for (int ks = 0; ks < 4; ++ks) {
            int off = ((2 * ks + hi) ^ rsw) << 3;
            short8 Va0 = *(const short8*)&Vb[q5 * 64 + off];
            short8 Va1 = *(const short8*)&Vb[(32 + q5) * 64 + off];
            O0 = __builtin_amdgcn_mfma_f32_32x32x16_bf16(Va0, pa[ks].s8, O0, 0, 0, 0);
            O1 = __builtin_amdgcn_mfma_f32_32x32x16_bf16(Va1, pa[ks].s8, O1, 0, 0, 0);
        }
        __builtin_amdgcn_s_setprio(0);

        __syncthreads();
    }

    // ---- combine partials: group B -> LDS, group A adds ----
    float* OxS = (float*)SMEM;                    // [4][64][33] floats
    float* lrX = (float*)(SMEM + 33792);          // [4][64]
    if (grp == 1) {
        float* dst = OxS + (size_t)(wq * 64 + lane) * 33;
        #pragma unroll
        for (int r = 0; r < 16; ++r) { dst[r] = O0[r]; dst[16 + r] = O1[r]; }
        lrX[wq * 64 + lane] = lrun;
    }
    __syncthreads();
    if (grp == 0) {
        const float* src = OxS + (size_t)(wq * 64 + lane) * 33;
        #pragma unroll
        for (int r = 0; r < 16; ++r) { O0[r] += src[r]; O1[r] += src[16 + r]; }
        lrun += lrX[wq * 64 + lane];

        // epilogue: per-wave transpose O^T -> row-major via private LDS region
        float invl = 1.f / lrun;
        float* oreg = (float*)(SMEM + 37888) + wq * (32 * 36);
        int orow = lane >> 1;
        int ocol = (lane & 1) * 16;

        #pragma unroll
        for (int r = 0; r < 16; ++r) {
            int dl = (r & 3) + 8 * (r >> 2) + 4 * hi;
            oreg[q5 * 36 + dl] = O0[r];
        }
        if (hi == 0) oreg[q5 * 36 + 32] = invl;
        asm volatile("" ::: "memory");
        {
            float iv = oreg[orow * 36 + 32];
            float* gout = out + ((size_t)b * LL + q0w + orow) * EE + h * DD + ocol;
            #pragma unroll
            for (int c = 0; c < 4; ++c) {
                float4 vv = *(float4*)&oreg[orow * 36 + ocol + 4 * c];
                vv.x *= iv; vv.y *= iv; vv.z *= iv; vv.w *= iv;
                *(float4*)&gout[4 * c] = vv;
            }
        }
        asm volatile("" ::: "memory");
        #pragma unroll
        for (int r = 0; r < 16; ++r) {
            int dl = (r & 3) + 8 * (r >> 2) + 4 * hi;
            oreg[q5 * 36 + dl] = O1[r];
        }
        asm volatile("" ::: "memory");
        {
            float iv = oreg[orow * 36 + 32];
            float* gout = out + ((size_t)b * LL + q0w + orow) * EE + h * DD + 32 + ocol;
            #pragma unroll
            for (int c = 0; c < 4; ++c) {
                float4 vv = *(float4*)&oreg[orow * 36 + ocol + 4 * c];
                vv.x *= iv; vv.y *= iv; vv.z *= iv; vv.w *= iv;
                *(float4*)&gout[4 * c] = vv;
            }
        }
    }
}

extern "C" void kernel_launch(void* const* d_in, const int* in_sizes, int n_in,
                              void* d_out, int out_size, void* d_ws, size_t ws_size,
                              hipStream_t stream) {
    const float* query = (const float*)d_in[0];
    const float* keys  = (const float*)d_in[1];
    const float* values = (const float*)d_in[2];
    const int* pad  = (const int*)d_in[3];
    const int* cau  = (const int*)d_in[4];
    const int* bern = (const int*)d_in[5];
    const float* conv_w = (const float*)d_in[6];
    const float* conv_b = (const float*)d_in[7];
    const float* Wv = (const float*)d_in[8];
    float* outp = (float*)d_out;

    const size_t per = (size_t)BB * HH * LL * DD;
    __hip_bfloat16* qcb = (__hip_bfloat16*)d_ws;
    __hip_bfloat16* ksb = qcb + per;
    __hip_bfloat16* vtb = ksb + per;
    float* pmax = (float*)(vtb + per);
    float* psum = pmax + (size_t)BB * HH * NCH * 64;
    float* maskf = psum + (size_t)BB * HH * NCH * 64;

    conv_kernel<<<BB * HH * (LL / 4), 256, 0, stream>>>(query, conv_w, conv_b, qcb);
    ksm_partial_kernel<<<BB * HH * NCH, 256, 0, stream>>>(keys, bern, pad, cau, pmax, psum, maskf);
    ksm_final_kernel<<<BB * HH * NCH, 256, 0, stream>>>(keys, bern, pmax, psum, ksb);
    vlin_kernel<<<BB * HH * (LL / 64), 256, 0, stream>>>(values, Wv, vtb);
    attn_mfma_kernel<<<BB * HH * 8, 512, 0, stream>>>(qcb, ksb, vtb, maskf, outp);
}

// Round 8
// 85.676 us; speedup vs baseline: 1.5289x; 1.3160x over previous
//
#include <hip/hip_runtime.h>
#include <hip/hip_bf16.h>
#include <math.h>

#define BB 4
#define LL 1024
#define EE 1024
#define HH 16
#define DD 64
#define NCH 8
#define CHROWS 128   // LL / NCH
#define K2C 0.04508422002777998f   // log2(e)/32
#define BIASC 7.2134752044448f     // 160 * K2C : fixed softmax bias

typedef __attribute__((ext_vector_type(8))) short short8;
typedef __attribute__((ext_vector_type(16))) float f32x16;
typedef __attribute__((ext_vector_type(4))) int int4v;

static __device__ __forceinline__ unsigned short bfbits(float x) {
    __hip_bfloat16 h = __float2bfloat16(x);
    return *(unsigned short*)&h;
}

#define CVTPK(dst, lo_, hi_) \
    asm("v_cvt_pk_bf16_f32 %0, %1, %2" : "=v"(dst) : "v"(lo_), "v"(hi_))
#define PLSWAP(x_, y_) \
    asm("v_permlane32_swap_b32 %0, %1" : "+v"(x_), "+v"(y_))

// ---------------------------------------------------------------------------
// Kernel 1 (fused prep): block-range dispatch
//   [0, 4096)    : grouped 3x3 conv -> bf16 qcb[bh][l][d]
//   [4096, 5120) : value linear -> transposed bf16 vt[bh][d][l]
//   [5120, 5632) : keys column-softmax chunk partials (+ maskf for h==0)
// ---------------------------------------------------------------------------
__global__ __launch_bounds__(256) void prep_kernel(
    const float* __restrict__ query,
    const float* __restrict__ conv_w,
    const float* __restrict__ conv_b,
    const float* __restrict__ values,
    const float* __restrict__ Wv,
    const float* __restrict__ keys,
    const int* __restrict__ bern,
    const int* __restrict__ pad,
    const int* __restrict__ cau,
    __hip_bfloat16* __restrict__ qcb,
    __hip_bfloat16* __restrict__ vt,
    float* __restrict__ pmax,
    float* __restrict__ psum,
    float* __restrict__ maskf) {
    __shared__ __align__(16) char SM[34048];
    int tid = threadIdx.x;
    int bid = blockIdx.x;

    if (bid < 4096) {
        // ---------------- conv ----------------
        int d = tid & 63;
        int lr = tid >> 6;
        int l0 = (bid & (LL / 4 - 1)) << 2;
        int bh = bid >> 8;
        int h = bh & (HH - 1);
        int b = bh >> 4;
        int l = l0 + lr;

        const float* w = conv_w + h * 9;
        float acc = conv_b[h];
        const float* qin = query + ((size_t)b * LL) * EE + h * DD;
        #pragma unroll
        for (int i = 0; i < 3; ++i) {
            int li = l + i - 1;
            if (li < 0 || li >= LL) continue;
            #pragma unroll
            for (int j = 0; j < 3; ++j) {
                int dj = d + j - 1;
                if (dj < 0 || dj >= DD) continue;
                acc += w[i * 3 + j] * qin[(size_t)li * EE + dj];
            }
        }
        qcb[((size_t)bh * LL + l) * DD + d] = __float2bfloat16(acc);
    } else if (bid < 5120) {
        // ---------------- vlin ----------------
        float (*WvS)[65] = (float(*)[65])SM;            // 16640 B
        float (*vs)[68]  = (float(*)[68])(SM + 16640);  // 17408 B
        int tile = bid - 4096;
        int lt = tile & 15;
        int bh = tile >> 4;
        int h = bh & (HH - 1);
        int b = bh >> 4;
        int l0 = lt * 64;

        for (int idx = tid; idx < 64 * 64; idx += 256)
            WvS[idx >> 6][idx & 63] = Wv[idx];
        const float* vin = values + ((size_t)b * LL + l0) * EE + h * DD;
        for (int idx = tid; idx < 1024; idx += 256) {
            int r = idx >> 4;
            int c4 = (idx & 15) << 2;
            *(float4*)&vs[r][c4] = *(const float4*)&vin[(size_t)r * EE + c4];
        }
        __syncthreads();

        int d = tid & 63;
        int r0 = (tid >> 6) * 16;
        float acc[16];
        #pragma unroll
        for (int r = 0; r < 16; ++r) acc[r] = 0.f;
        for (int k = 0; k < 64; ++k) {
            float wv = WvS[d][k];
            #pragma unroll
            for (int r = 0; r < 16; ++r) acc[r] += vs[r0 + r][k] * wv;
        }
        union { unsigned short us[16]; uint4 v[2]; } pk;
        #pragma unroll
        for (int r = 0; r < 16; ++r) pk.us[r] = bfbits(acc[r]);
        __hip_bfloat16* vo = vt + ((size_t)bh * DD + d) * LL + l0 + r0;
        *(uint4*)&vo[0] = pk.v[0];
        *(uint4*)&vo[8] = pk.v[1];
    } else {
        // ---------------- ksm_partial ----------------
        float (*sm)[64] = (float(*)[64])SM;            // 1024 B
        float (*ss)[64] = (float(*)[64])(SM + 1024);   // 1024 B
        int blk = bid - 5120;
        int d = tid & 63;
        int seg = tid >> 6;
        int ch = blk & (NCH - 1);
        int bh = blk >> 3;
        int h = bh & (HH - 1);
        int b = bh >> 4;
        int r0 = ch * CHROWS + seg * 32;

        if (h == 0 && tid < CHROWS) {
            int l = ch * CHROWS + tid;
            maskf[b * LL + l] = ((pad[b * LL + l] != 0) & (cau[b * LL + l] != 0)) ? -1e20f : 0.f;
        }

        const float* kin = keys + ((size_t)b * LL + r0) * EE + h * DD + d;
        const int* bm = bern + (size_t)bh * LL + r0;

        float v[32];
        #pragma unroll
        for (int i = 0; i < 32; ++i) v[i] = kin[(size_t)i * EE];
        float m = -INFINITY;
        #pragma unroll
        for (int i = 0; i < 32; ++i)
            if (bm[i]) m = fmaxf(m, v[i]);
        float s = 0.f;
        #pragma unroll
        for (int i = 0; i < 32; ++i)
            if (bm[i]) s += __expf(v[i] - m);

        sm[seg][d] = m;
        ss[seg][d] = s;
        __syncthreads();
        if (seg == 0) {
            float M = sm[0][d];
            #pragma unroll
            for (int t = 1; t < 4; ++t) M = fmaxf(M, sm[t][d]);
            float S = 0.f;
            if (M > -INFINITY) {
                #pragma unroll
                for (int t = 0; t < 4; ++t)
                    if (sm[t][d] > -INFINITY) S += ss[t][d] * __expf(sm[t][d] - M);
            }
            pmax[(size_t)blk * 64 + d] = M;
            psum[(size_t)blk * 64 + d] = S;
        }
    }
}

// ---------------------------------------------------------------------------
// Kernel 2: combine chunk partials; normalize chunk; write bf16 ksb.
// ---------------------------------------------------------------------------
__global__ __launch_bounds__(256) void ksm_final_kernel(
    const float* __restrict__ keys,
    const int* __restrict__ bern,
    const float* __restrict__ pmax,
    const float* __restrict__ psum,
    __hip_bfloat16* __restrict__ ksb) {
    int tid = threadIdx.x;
    int d = tid & 63;
    int seg = tid >> 6;
    int blk = blockIdx.x;
    int ch = blk & (NCH - 1);
    int bh = blk >> 3;
    int h = bh & (HH - 1);
    int b = bh >> 4;
    int r0 = ch * CHROWS + seg * 32;

    const float* pm = pmax + (size_t)bh * NCH * 64;
    const float* ps = psum + (size_t)bh * NCH * 64;
    float M = -INFINITY;
    #pragma unroll
    for (int c = 0; c < NCH; ++c) M = fmaxf(M, pm[c * 64 + d]);
    float S = 0.f;
    #pragma unroll
    for (int c = 0; c < NCH; ++c) {
        float mi = pm[c * 64 + d];
        if (mi > -INFINITY) S += ps[c * 64 + d] * __expf(mi - M);
    }
    float inv = 1.f / S;

    const float* kin = keys + ((size_t)b * LL + r0) * EE + h * DD + d;
    const int* bm = bern + (size_t)bh * LL + r0;
    __hip_bfloat16* kout = ksb + ((size_t)bh * LL + r0) * DD + d;
    #pragma unroll
    for (int i = 0; i < 32; ++i) {
        float val = bm[i] ? __expf(kin[(size_t)i * EE] - M) * inv : 0.f;
        kout[(size_t)i * DD] = __float2bfloat16(val);
    }
}

// ---------------------------------------------------------------------------
// Kernel 3: swapped-QK^T MFMA flash attention (32x32x16), FIXED-BIAS softmax:
// pv = exp2(fma(S, K2C, fma(mask, K2C, -BIASC))) — no row max, no rescale,
// masked cols -> exact 0. 4 waves x 32 q-rows; KVBLK=64 double-buffered LDS.
// ---------------------------------------------------------------------------
__global__ __launch_bounds__(256) void attn_mfma_kernel(
    const __hip_bfloat16* __restrict__ qcb,
    const __hip_bfloat16* __restrict__ ksb,
    const __hip_bfloat16* __restrict__ vtb,
    const float* __restrict__ maskf,
    float* __restrict__ out) {
    __shared__ __align__(16) short KsS[2][4096];
    __shared__ __align__(16) short VtS[2][4096];
    __shared__ __align__(16) float OutS[4][32 * 36];

    int tid = threadIdx.x;
    int lane = tid & 63;
    int w = tid >> 6;                  // 4 waves
    int q5 = lane & 31;
    int hi = lane >> 5;

    // XCD swizzle: 512 blocks; 64 consecutive swz per XCD -> 8 bh in its L2
    int bid = blockIdx.x;
    int swz = (bid & 7) * 64 + (bid >> 3);
    int bh = swz >> 3;
    int qb = swz & 7;
    int b = bh >> 4;
    int h = bh & 15;
    int q0w = qb * 128 + w * 32;

    const float* mb = maskf + b * LL;

    // staging geometry: 256 threads x 2 its = 64 rows x 8 chunks of 8 bf16
    int srow = tid >> 3;
    int sch = tid & 7;
    int ssw = (sch ^ (srow & 7)) << 3;
    const __hip_bfloat16* kg = ksb + (size_t)bh * LL * DD + (size_t)srow * DD + ssw;
    const __hip_bfloat16* vg = vtb + (size_t)bh * DD * LL + (size_t)srow * LL + ssw;

    short8 Qf[4];
    {
        const short* qrow = (const short*)qcb + ((size_t)bh * LL + q0w + q5) * DD + 8 * hi;
        #pragma unroll
        for (int i = 0; i < 4; ++i)
            Qf[i] = *(const short8*)(qrow + 16 * i);
    }

    // prologue: stage tile 0 into buf 0
    #pragma unroll
    for (int it = 0; it < 2; ++it) {
        __builtin_amdgcn_global_load_lds(
            (const __attribute__((address_space(1))) void*)(kg + (size_t)it * 32 * DD),
            (__attribute__((address_space(3))) void*)&KsS[0][(it * 4 + w) * 512], 16, 0, 0);
        __builtin_amdgcn_global_load_lds(
            (const __attribute__((address_space(1))) void*)(vg + (size_t)it * 32 * LL),
            (__attribute__((address_space(3))) void*)&VtS[0][(it * 4 + w) * 512], 16, 0, 0);
    }
    __syncthreads();

    f32x16 O0, O1;
    #pragma unroll
    for (int e = 0; e < 16; ++e) { O0[e] = 0.f; O1[e] = 0.f; }
    float lrun = 0.f;

    for (int kt = 0; kt < 16; ++kt) {
        int buf = kt & 1;
        int k0 = kt * 64;
        if (kt < 15) {
            int k0n = k0 + 64;
            #pragma unroll
            for (int it = 0; it < 2; ++it) {
                __builtin_amdgcn_global_load_lds(
                    (const __attribute__((address_space(1))) void*)(kg + (size_t)(k0n + it * 32) * DD),
                    (__attribute__((address_space(3))) void*)&KsS[buf ^ 1][(it * 4 + w) * 512], 16, 0, 0);
                __builtin_amdgcn_global_load_lds(
                    (const __attribute__((address_space(1))) void*)(vg + k0n + (size_t)it * 32 * LL),
                    (__attribute__((address_space(3))) void*)&VtS[buf ^ 1][(it * 4 + w) * 512], 16, 0, 0);
            }
        }

        const short* Kb = KsS[buf];
        const short* Vb = VtS[buf];
        int rsw = q5 & 7;

        // hoisted: K frags, V frags (LDS), mask float4s (global, L2-hot)
        short8 Ka0[4], Ka1[4], Va0[4], Va1[4];
        #pragma unroll
        for (int i = 0; i < 4; ++i) {
            int off = ((2 * i + hi) ^ rsw) << 3;
            Ka0[i] = *(const short8*)&Kb[q5 * 64 + off];
            Ka1[i] = *(const short8*)&Kb[(32 + q5) * 64 + off];
            Va0[i] = *(const short8*)&Vb[q5 * 64 + off];
            Va1[i] = *(const short8*)&Vb[(32 + q5) * 64 + off];
        }
        float4 mk0[4], mk1[4];
        #pragma unroll
        for (int a = 0; a < 4; ++a) {
            mk0[a] = *(const float4*)&mb[k0 + 8 * a + 4 * hi];
            mk1[a] = *(const float4*)&mb[k0 + 32 + 8 * a + 4 * hi];
        }

        f32x16 S0, S1;
        #pragma unroll
        for (int e = 0; e < 16; ++e) { S0[e] = 0.f; S1[e] = 0.f; }
        __builtin_amdgcn_s_setprio(1);
        #pragma unroll
        for (int i = 0; i < 4; ++i) {
            S0 = __builtin_amdgcn_mfma_f32_32x32x16_bf16(Ka0[i], Qf[i], S0, 0, 0, 0);
            S1 = __builtin_amdgcn_mfma_f32_32x32x16_bf16(Ka1[i], Qf[i], S1, 0, 0, 0);
        }
        __builtin_amdgcn_s_setprio(0);

        // fixed-bias softmax: pv = exp2(S*K2C + (mask*K2C - BIASC))
        float pv[32];
        #pragma unroll
        for (int a = 0; a < 4; ++a) {
            #pragma unroll
            for (int j = 0; j < 4; ++j) {
                float ma0 = __builtin_fmaf(mk0[a][j], K2C, -BIASC);
                float ma1 = __builtin_fmaf(mk1[a][j], K2C, -BIASC);
                pv[4 * a + j]      = exp2f(__builtin_fmaf(S0[4 * a + j], K2C, ma0));
                pv[16 + 4 * a + j] = exp2f(__builtin_fmaf(S1[4 * a + j], K2C, ma1));
            }
        }

        float t16[16];
        #pragma unroll
        for (int r = 0; r < 16; ++r) t16[r] = pv[r] + pv[r + 16];
        float t8[8];
        #pragma unroll
        for (int r = 0; r < 8; ++r) t8[r] = t16[r] + t16[r + 8];
        float rs = ((t8[0] + t8[1]) + (t8[2] + t8[3])) + ((t8[4] + t8[5]) + (t8[6] + t8[7]));
        rs += __shfl_xor(rs, 32, 64);
        lrun += rs;

        // pack P -> B-fragments via cvt_pk + permlane32_swap
        union PW { int4v i4; short8 s8; } pa[4];
        #pragma unroll
        for (int st = 0; st < 2; ++st) {
            int c0, d0, c1, d1, c2, d2, c3, d3;
            CVTPK(c0, pv[16 * st + 0], pv[16 * st + 1]);
            CVTPK(d0, pv[16 * st + 4], pv[16 * st + 5]);
            PLSWAP(c0, d0);
            CVTPK(c1, pv[16 * st + 2], pv[16 * st + 3]);
            CVTPK(d1, pv[16 * st + 6], pv[16 * st + 7]);
            PLSWAP(c1, d1);
            pa[2 * st].i4 = (int4v){c0, c1, d0, d1};
            CVTPK(c2, pv[16 * st + 8], pv[16 * st + 9]);
            CVTPK(d2, pv[16 * st + 12], pv[16 * st + 13]);
            PLSWAP(c2, d2);
            CVTPK(c3, pv[16 * st + 10], pv[16 * st + 11]);
            CVTPK(d3, pv[16 * st + 14], pv[16 * st + 15]);
            PLSWAP(c3, d3);
            pa[2 * st + 1].i4 = (int4v){c2, c3, d2, d3};
        }

        __builtin_amdgcn_s_setprio(1);
        #pragma unroll
        for (int ks = 0; ks < 4; ++ks) {
            O0 = __builtin_amdgcn_mfma_f32_32x32x16_bf16(Va0[ks], pa[ks].s8, O0, 0, 0, 0);
            O1 = __builtin_amdgcn_mfma_f32_32x32x16_bf16(Va1[ks], pa[ks].s8, O1, 0, 0, 0);
        }
        __builtin_amdgcn_s_setprio(0);

        if (kt < 15) __syncthreads();
    }

    // epilogue: per-wave transpose O^T -> row-major via private LDS region
    float invl = 1.f / lrun;
    float* oreg = OutS[w];
    int orow = lane >> 1;
    int ocol = (lane & 1) * 16;

    #pragma unroll
    for (int r = 0; r < 16; ++r) {
        int dl = (r & 3) + 8 * (r >> 2) + 4 * hi;
        oreg[q5 * 36 + dl] = O0[r];
    }
    if (hi == 0) oreg[q5 * 36 + 32] = invl;
    asm volatile("" ::: "memory");
    {
        float iv = oreg[orow * 36 + 32];
        float* gout = out + ((size_t)b * LL + q0w + orow) * EE + h * DD + ocol;
        #pragma unroll
        for (int c = 0; c < 4; ++c) {
            float4 vv = *(float4*)&oreg[orow * 36 + ocol + 4 * c];
            vv.x *= iv; vv.y *= iv; vv.z *= iv; vv.w *= iv;
            *(float4*)&gout[4 * c] = vv;
        }
    }
    asm volatile("" ::: "memory");
    #pragma unroll
    for (int r = 0; r < 16; ++r) {
        int dl = (r & 3) + 8 * (r >> 2) + 4 * hi;
        oreg[q5 * 36 + dl] = O1[r];
    }
    asm volatile("" ::: "memory");
    {
        float iv = oreg[orow * 36 + 32];
        float* gout = out + ((size_t)b * LL + q0w + orow) * EE + h * DD + 32 + ocol;
        #pragma unroll
        for (int c = 0; c < 4; ++c) {
            float4 vv = *(float4*)&oreg[orow * 36 + ocol + 4 * c];
            vv.x *= iv; vv.y *= iv; vv.z *= iv; vv.w *= iv;
            *(float4*)&gout[4 * c] = vv;
        }
    }
}

extern "C" void kernel_launch(void* const* d_in, const int* in_sizes, int n_in,
                              void* d_out, int out_size, void* d_ws, size_t ws_size,
                              hipStream_t stream) {
    const float* query = (const float*)d_in[0];
    const float* keys  = (const float*)d_in[1];
    const float* values = (const float*)d_in[2];
    const int* pad  = (const int*)d_in[3];
    const int* cau  = (const int*)d_in[4];
    const int* bern = (const int*)d_in[5];
    const float* conv_w = (const float*)d_in[6];
    const float* conv_b = (const float*)d_in[7];
    const float* Wv = (const float*)d_in[8];
    float* outp = (float*)d_out;

    const size_t per = (size_t)BB * HH * LL * DD;
    __hip_bfloat16* qcb = (__hip_bfloat16*)d_ws;
    __hip_bfloat16* ksb = qcb + per;
    __hip_bfloat16* vtb = ksb + per;
    float* pmax = (float*)(vtb + per);
    float* psum = pmax + (size_t)BB * HH * NCH * 64;
    float* maskf = psum + (size_t)BB * HH * NCH * 64;

    prep_kernel<<<5632, 256, 0, stream>>>(query, conv_w, conv_b, values, Wv,
                                          keys, bern, pad, cau,
                                          qcb, vtb, pmax, psum, maskf);
    ksm_final_kernel<<<BB * HH * NCH, 256, 0, stream>>>(keys, bern, pmax, psum, ksb);
    attn_mfma_kernel<<<BB * HH * 8, 256, 0, stream>>>(qcb, ksb, vtb, maskf, outp);
}

// Round 9
// 85.177 us; speedup vs baseline: 1.5379x; 1.0059x over previous
//
#include <hip/hip_runtime.h>
#include <hip/hip_bf16.h>
#include <math.h>

#define BB 4
#define LL 1024
#define EE 1024
#define HH 16
#define DD 64
#define NCH 8
#define CHROWS 128   // LL / NCH
#define K2C 0.04508422002777998f   // log2(e)/32
#define BIASC 7.2134752044448f     // 160 * K2C : fixed softmax bias

typedef __attribute__((ext_vector_type(8))) short short8;
typedef __attribute__((ext_vector_type(16))) float f32x16;
typedef __attribute__((ext_vector_type(4))) int int4v;

static __device__ __forceinline__ unsigned short bfbits(float x) {
    __hip_bfloat16 h = __float2bfloat16(x);
    return *(unsigned short*)&h;
}

#define CVTPK(dst, lo_, hi_) \
    asm("v_cvt_pk_bf16_f32 %0, %1, %2" : "=v"(dst) : "v"(lo_), "v"(hi_))
#define PLSWAP(x_, y_) \
    asm("v_permlane32_swap_b32 %0, %1" : "+v"(x_), "+v"(y_))

// ---------------------------------------------------------------------------
// Kernel 1 (fused prep): block-range dispatch
//   [0, 4096)    : grouped 3x3 conv -> bf16 qcb[bh][l][d]
//   [4096, 5120) : value linear -> transposed bf16 vt[bh][d][l]
//   [5120, 5632) : keys column-softmax chunk partials (+ maskf for h==0)
// ---------------------------------------------------------------------------
__global__ __launch_bounds__(256) void prep_kernel(
    const float* __restrict__ query,
    const float* __restrict__ conv_w,
    const float* __restrict__ conv_b,
    const float* __restrict__ values,
    const float* __restrict__ Wv,
    const float* __restrict__ keys,
    const int* __restrict__ bern,
    const int* __restrict__ pad,
    const int* __restrict__ cau,
    __hip_bfloat16* __restrict__ qcb,
    __hip_bfloat16* __restrict__ vt,
    float* __restrict__ pmax,
    float* __restrict__ psum,
    float* __restrict__ maskf) {
    __shared__ __align__(16) char SM[34048];
    int tid = threadIdx.x;
    int bid = blockIdx.x;

    if (bid < 4096) {
        // ---------------- conv ----------------
        int d = tid & 63;
        int lr = tid >> 6;
        int l0 = (bid & (LL / 4 - 1)) << 2;
        int bh = bid >> 8;
        int h = bh & (HH - 1);
        int b = bh >> 4;
        int l = l0 + lr;

        const float* w = conv_w + h * 9;
        float acc = conv_b[h];
        const float* qin = query + ((size_t)b * LL) * EE + h * DD;
        #pragma unroll
        for (int i = 0; i < 3; ++i) {
            int li = l + i - 1;
            if (li < 0 || li >= LL) continue;
            #pragma unroll
            for (int j = 0; j < 3; ++j) {
                int dj = d + j - 1;
                if (dj < 0 || dj >= DD) continue;
                acc += w[i * 3 + j] * qin[(size_t)li * EE + dj];
            }
        }
        qcb[((size_t)bh * LL + l) * DD + d] = __float2bfloat16(acc);
    } else if (bid < 5120) {
        // ---------------- vlin ----------------
        float (*WvS)[65] = (float(*)[65])SM;            // 16640 B
        float (*vs)[68]  = (float(*)[68])(SM + 16640);  // 17408 B
        int tile = bid - 4096;
        int lt = tile & 15;
        int bh = tile >> 4;
        int h = bh & (HH - 1);
        int b = bh >> 4;
        int l0 = lt * 64;

        for (int idx = tid; idx < 64 * 64; idx += 256)
            WvS[idx >> 6][idx & 63] = Wv[idx];
        const float* vin = values + ((size_t)b * LL + l0) * EE + h * DD;
        for (int idx = tid; idx < 1024; idx += 256) {
            int r = idx >> 4;
            int c4 = (idx & 15) << 2;
            *(float4*)&vs[r][c4] = *(const float4*)&vin[(size_t)r * EE + c4];
        }
        __syncthreads();

        int d = tid & 63;
        int r0 = (tid >> 6) * 16;
        float acc[16];
        #pragma unroll
        for (int r = 0; r < 16; ++r) acc[r] = 0.f;
        for (int k = 0; k < 64; ++k) {
            float wv = WvS[d][k];
            #pragma unroll
            for (int r = 0; r < 16; ++r) acc[r] += vs[r0 + r][k] * wv;
        }
        union { unsigned short us[16]; uint4 v[2]; } pk;
        #pragma unroll
        for (int r = 0; r < 16; ++r) pk.us[r] = bfbits(acc[r]);
        __hip_bfloat16* vo = vt + ((size_t)bh * DD + d) * LL + l0 + r0;
        *(uint4*)&vo[0] = pk.v[0];
        *(uint4*)&vo[8] = pk.v[1];
    } else {
        // ---------------- ksm_partial ----------------
        float (*sm)[64] = (float(*)[64])SM;
        float (*ss)[64] = (float(*)[64])(SM + 1024);
        int blk = bid - 5120;
        int d = tid & 63;
        int seg = tid >> 6;
        int ch = blk & (NCH - 1);
        int bh = blk >> 3;
        int h = bh & (HH - 1);
        int b = bh >> 4;
        int r0 = ch * CHROWS + seg * 32;

        if (h == 0 && tid < CHROWS) {
            int l = ch * CHROWS + tid;
            maskf[b * LL + l] = ((pad[b * LL + l] != 0) & (cau[b * LL + l] != 0)) ? -1e20f : 0.f;
        }

        const float* kin = keys + ((size_t)b * LL + r0) * EE + h * DD + d;
        const int* bm = bern + (size_t)bh * LL + r0;

        float v[32];
        #pragma unroll
        for (int i = 0; i < 32; ++i) v[i] = kin[(size_t)i * EE];
        float m = -INFINITY;
        #pragma unroll
        for (int i = 0; i < 32; ++i)
            if (bm[i]) m = fmaxf(m, v[i]);
        float s = 0.f;
        #pragma unroll
        for (int i = 0; i < 32; ++i)
            if (bm[i]) s += __expf(v[i] - m);

        sm[seg][d] = m;
        ss[seg][d] = s;
        __syncthreads();
        if (seg == 0) {
            float M = sm[0][d];
            #pragma unroll
            for (int t = 1; t < 4; ++t) M = fmaxf(M, sm[t][d]);
            float S = 0.f;
            if (M > -INFINITY) {
                #pragma unroll
                for (int t = 0; t < 4; ++t)
                    if (sm[t][d] > -INFINITY) S += ss[t][d] * __expf(sm[t][d] - M);
            }
            pmax[(size_t)blk * 64 + d] = M;
            psum[(size_t)blk * 64 + d] = S;
        }
    }
}

// ---------------------------------------------------------------------------
// Kernel 2: combine chunk partials; normalize chunk; write bf16 ksb.
// ---------------------------------------------------------------------------
__global__ __launch_bounds__(256) void ksm_final_kernel(
    const float* __restrict__ keys,
    const int* __restrict__ bern,
    const float* __restrict__ pmax,
    const float* __restrict__ psum,
    __hip_bfloat16* __restrict__ ksb) {
    int tid = threadIdx.x;
    int d = tid & 63;
    int seg = tid >> 6;
    int blk = blockIdx.x;
    int ch = blk & (NCH - 1);
    int bh = blk >> 3;
    int h = bh & (HH - 1);
    int b = bh >> 4;
    int r0 = ch * CHROWS + seg * 32;

    const float* pm = pmax + (size_t)bh * NCH * 64;
    const float* ps = psum + (size_t)bh * NCH * 64;
    float M = -INFINITY;
    #pragma unroll
    for (int c = 0; c < NCH; ++c) M = fmaxf(M, pm[c * 64 + d]);
    float S = 0.f;
    #pragma unroll
    for (int c = 0; c < NCH; ++c) {
        float mi = pm[c * 64 + d];
        if (mi > -INFINITY) S += ps[c * 64 + d] * __expf(mi - M);
    }
    float inv = 1.f / S;

    const float* kin = keys + ((size_t)b * LL + r0) * EE + h * DD + d;
    const int* bm = bern + (size_t)bh * LL + r0;
    __hip_bfloat16* kout = ksb + ((size_t)bh * LL + r0) * DD + d;
    #pragma unroll
    for (int i = 0; i < 32; ++i) {
        float val = bm[i] ? __expf(kin[(size_t)i * EE] - M) * inv : 0.f;
        kout[(size_t)i * DD] = __float2bfloat16(val);
    }
}

// ---------------------------------------------------------------------------
// Kernel 3: swapped-QK^T MFMA flash attention, KV-SPLIT across wave groups,
// fixed-bias softmax (partials add linearly). 8 waves: grp0 even tiles,
// grp1 odd tiles; 4 LDS tile slots; 8 barriers total. NO min-waves bound
// (round-7 lesson: launch_bounds(512,4) caused spill: VGPR 64, 31MB scratch).
// ---------------------------------------------------------------------------
__global__ __launch_bounds__(512) void attn_mfma_kernel(
    const __hip_bfloat16* __restrict__ qcb,
    const __hip_bfloat16* __restrict__ ksb,
    const __hip_bfloat16* __restrict__ vtb,
    const float* __restrict__ maskf,
    float* __restrict__ out) {
    __shared__ __align__(16) char SMEM[65536];
    short* KsS = (short*)SMEM;                // [4][4096] K tile slots
    short* VtS = (short*)(SMEM + 32768);      // [4][4096] V^T tile slots

    int tid = threadIdx.x;
    int lane = tid & 63;
    int w = tid >> 6;          // 0..7
    int grp = w >> 2;          // 0: even tiles, 1: odd tiles
    int wq = w & 3;            // q-chunk within block
    int q5 = lane & 31;
    int hi = lane >> 5;

    // XCD swizzle: 512 blocks; 64 consecutive swz per XCD -> 8 bh in its L2
    int bid = blockIdx.x;
    int swz = (bid & 7) * 64 + (bid >> 3);
    int bh = swz >> 3;
    int qb = swz & 7;
    int b = bh >> 4;
    int h = bh & 15;
    int q0w = qb * 128 + wq * 32;

    const float* mb = maskf + b * LL;

    // staging geometry: 512 threads = 64 rows x 8 chunks of 8 bf16 per tile
    int srow = tid >> 3;
    int sch = tid & 7;
    int ssw = (sch ^ (srow & 7)) << 3;
    const short* kg = (const short*)ksb + (size_t)bh * LL * DD + (size_t)srow * DD + ssw;
    const short* vg = (const short*)vtb + (size_t)bh * DD * LL + (size_t)srow * LL + ssw;

    short8 Qf[4];
    {
        const short* qrow = (const short*)qcb + ((size_t)bh * LL + q0w + q5) * DD + 8 * hi;
        #pragma unroll
        for (int i = 0; i < 4; ++i)
            Qf[i] = *(const short8*)(qrow + 16 * i);
    }

    // prologue: tiles 0,1 -> slots 0,1
    #pragma unroll
    for (int t = 0; t < 2; ++t) {
        __builtin_amdgcn_global_load_lds(
            (const __attribute__((address_space(1))) void*)(kg + (size_t)t * 64 * DD),
            (__attribute__((address_space(3))) void*)&KsS[t * 4096 + (tid >> 3) * 64 + (0)], 16, 0, 0);
        __builtin_amdgcn_global_load_lds(
            (const __attribute__((address_space(1))) void*)(vg + t * 64),
            (__attribute__((address_space(3))) void*)&VtS[t * 4096 + (tid >> 3) * 64 + (0)], 16, 0, 0);
    }
    __syncthreads();

    f32x16 O0, O1;
    #pragma unroll
    for (int e = 0; e < 16; ++e) { O0[e] = 0.f; O1[e] = 0.f; }
    float lrun = 0.f;

    for (int j = 0; j < 8; ++j) {
        // prefetch tiles 2j+2, 2j+3 (slots consumed at step j-1; safe after
        // the barrier that ended step j-1)
        if (j < 7) {
            #pragma unroll
            for (int t = 0; t < 2; ++t) {
                int tl = 2 * j + 2 + t;
                int sl = tl & 3;
                __builtin_amdgcn_global_load_lds(
                    (const __attribute__((address_space(1))) void*)(kg + (size_t)tl * 64 * DD),
                    (__attribute__((address_space(3))) void*)&KsS[sl * 4096 + (tid >> 3) * 64], 16, 0, 0);
                __builtin_amdgcn_global_load_lds(
                    (const __attribute__((address_space(1))) void*)(vg + tl * 64),
                    (__attribute__((address_space(3))) void*)&VtS[sl * 4096 + (tid >> 3) * 64], 16, 0, 0);
            }
        }

        int slot = (2 * j + grp) & 3;
        int k0 = j * 128 + 64 * grp;
        const short* Kb = &KsS[slot * 4096];
        const short* Vb = &VtS[slot * 4096];
        int rsw = q5 & 7;

        // hoisted: K frags, V frags (LDS), mask float4s (global, L2-hot)
        short8 Ka0[4], Ka1[4], Va0[4], Va1[4];
        #pragma unroll
        for (int i = 0; i < 4; ++i) {
            int off = ((2 * i + hi) ^ rsw) << 3;
            Ka0[i] = *(const short8*)&Kb[q5 * 64 + off];
            Ka1[i] = *(const short8*)&Kb[(32 + q5) * 64 + off];
            Va0[i] = *(const short8*)&Vb[q5 * 64 + off];
            Va1[i] = *(const short8*)&Vb[(32 + q5) * 64 + off];
        }
        float4 mk0[4], mk1[4];
        #pragma unroll
        for (int a = 0; a < 4; ++a) {
            mk0[a] = *(const float4*)&mb[k0 + 8 * a + 4 * hi];
            mk1[a] = *(const float4*)&mb[k0 + 32 + 8 * a + 4 * hi];
        }

        f32x16 S0, S1;
        #pragma unroll
        for (int e = 0; e < 16; ++e) { S0[e] = 0.f; S1[e] = 0.f; }
        __builtin_amdgcn_s_setprio(1);
        #pragma unroll
        for (int i = 0; i < 4; ++i) {
            S0 = __builtin_amdgcn_mfma_f32_32x32x16_bf16(Ka0[i], Qf[i], S0, 0, 0, 0);
            S1 = __builtin_amdgcn_mfma_f32_32x32x16_bf16(Ka1[i], Qf[i], S1, 0, 0, 0);
        }
        __builtin_amdgcn_s_setprio(0);

        // fixed-bias softmax: pv = exp2(S*K2C + (mask*K2C - BIASC))
        float pv[32];
        #pragma unroll
        for (int a = 0; a < 4; ++a) {
            #pragma unroll
            for (int jj = 0; jj < 4; ++jj) {
                float ma0 = __builtin_fmaf(mk0[a][jj], K2C, -BIASC);
                float ma1 = __builtin_fmaf(mk1[a][jj], K2C, -BIASC);
                pv[4 * a + jj]      = exp2f(__builtin_fmaf(S0[4 * a + jj], K2C, ma0));
                pv[16 + 4 * a + jj] = exp2f(__builtin_fmaf(S1[4 * a + jj], K2C, ma1));
            }
        }

        float t16[16];
        #pragma unroll
        for (int r = 0; r < 16; ++r) t16[r] = pv[r] + pv[r + 16];
        float t8[8];
        #pragma unroll
        for (int r = 0; r < 8; ++r) t8[r] = t16[r] + t16[r + 8];
        float rs = ((t8[0] + t8[1]) + (t8[2] + t8[3])) + ((t8[4] + t8[5]) + (t8[6] + t8[7]));
        rs += __shfl_xor(rs, 32, 64);
        lrun += rs;

        // pack P -> B-fragments via cvt_pk + permlane32_swap
        union PW { int4v i4; short8 s8; } pa[4];
        #pragma unroll
        for (int st = 0; st < 2; ++st) {
            int c0, d0, c1, d1, c2, d2, c3, d3;
            CVTPK(c0, pv[16 * st + 0], pv[16 * st + 1]);
            CVTPK(d0, pv[16 * st + 4], pv[16 * st + 5]);
            PLSWAP(c0, d0);
            CVTPK(c1, pv[16 * st + 2], pv[16 * st + 3]);
            CVTPK(d1, pv[16 * st + 6], pv[16 * st + 7]);
            PLSWAP(c1, d1);
            pa[2 * st].i4 = (int4v){c0, c1, d0, d1};
            CVTPK(c2, pv[16 * st + 8], pv[16 * st + 9]);
            CVTPK(d2, pv[16 * st + 12], pv[16 * st + 13]);
            PLSWAP(c2, d2);
            CVTPK(c3, pv[16 * st + 10], pv[16 * st + 11]);
            CVTPK(d3, pv[16 * st + 14], pv[16 * st + 15]);
            PLSWAP(c3, d3);
            pa[2 * st + 1].i4 = (int4v){c2, c3, d2, d3};
        }

        __builtin_amdgcn_s_setprio(1);
        #pragma unroll
        for (int ks = 0; ks < 4; ++ks) {
            O0 = __builtin_amdgcn_mfma_f32_32x32x16_bf16(Va0[ks], pa[ks].s8, O0, 0, 0, 0);
            O1 = __builtin_amdgcn_mfma_f32_32x32x16_bf16(Va1[ks], pa[ks].s8, O1, 0, 0, 0);
        }
        __builtin_amdgcn_s_setprio(0);

        __syncthreads();
    }

    // ---- combine partials: group B -> LDS, group A adds ----
    float* OxS = (float*)SMEM;                    // [4][64][33] floats = 33792B
    float* lrX = (float*)(SMEM + 33792);          // [4][64] = 1024B
    if (grp == 1) {
        float* dst = OxS + (size_t)(wq * 64 + lane) * 33;
        #pragma unroll
        for (int r = 0; r < 16; ++r) { dst[r] = O0[r]; dst[16 + r] = O1[r]; }
        lrX[wq * 64 + lane] = lrun;
    }
    __syncthreads();
    if (grp == 0) {
        const float* src = OxS + (size_t)(wq * 64 + lane) * 33;
        #pragma unroll
        for (int r = 0; r < 16; ++r) { O0[r] += src[r]; O1[r] += src[16 + r]; }
        lrun += lrX[wq * 64 + lane];

        // epilogue: per-wave transpose O^T -> row-major via private LDS region
        float invl = 1.f / lrun;
        float* oreg = (float*)(SMEM + 36864) + wq * (32 * 36);  // 18432B region
        int orow = lane >> 1;
        int ocol = (lane & 1) * 16;

        #pragma unroll
        for (int r = 0; r < 16; ++r) {
            int dl = (r & 3) + 8 * (r >> 2) + 4 * hi;
            oreg[q5 * 36 + dl] = O0[r];
        }
        if (hi == 0) oreg[q5 * 36 + 32] = invl;
        asm volatile("" ::: "memory");
        {
            float iv = oreg[orow * 36 + 32];
            float* gout = out + ((size_t)b * LL + q0w + orow) * EE + h * DD + ocol;
            #pragma unroll
            for (int c = 0; c < 4; ++c) {
                float4 vv = *(float4*)&oreg[orow * 36 + ocol + 4 * c];
                vv.x *= iv; vv.y *= iv; vv.z *= iv; vv.w *= iv;
                *(float4*)&gout[4 * c] = vv;
            }
        }
        asm volatile("" ::: "memory");
        #pragma unroll
        for (int r = 0; r < 16; ++r) {
            int dl = (r & 3) + 8 * (r >> 2) + 4 * hi;
            oreg[q5 * 36 + dl] = O1[r];
        }
        asm volatile("" ::: "memory");
        {
            float iv = oreg[orow * 36 + 32];
            float* gout = out + ((size_t)b * LL + q0w + orow) * EE + h * DD + 32 + ocol;
            #pragma unroll
            for (int c = 0; c < 4; ++c) {
                float4 vv = *(float4*)&oreg[orow * 36 + ocol + 4 * c];
                vv.x *= iv; vv.y *= iv; vv.z *= iv; vv.w *= iv;
                *(float4*)&gout[4 * c] = vv;
            }
        }
    }
}

extern "C" void kernel_launch(void* const* d_in, const int* in_sizes, int n_in,
                              void* d_out, int out_size, void* d_ws, size_t ws_size,
                              hipStream_t stream) {
    const float* query = (const float*)d_in[0];
    const float* keys  = (const float*)d_in[1];
    const float* values = (const float*)d_in[2];
    const int* pad  = (const int*)d_in[3];
    const int* cau  = (const int*)d_in[4];
    const int* bern = (const int*)d_in[5];
    const float* conv_w = (const float*)d_in[6];
    const float* conv_b = (const float*)d_in[7];
    const float* Wv = (const float*)d_in[8];
    float* outp = (float*)d_out;

    const size_t per = (size_t)BB * HH * LL * DD;
    __hip_bfloat16* qcb = (__hip_bfloat16*)d_ws;
    __hip_bfloat16* ksb = qcb + per;
    __hip_bfloat16* vtb = ksb + per;
    float* pmax = (float*)(vtb + per);
    float* psum = pmax + (size_t)BB * HH * NCH * 64;
    float* maskf = psum + (size_t)BB * HH * NCH * 64;

    prep_kernel<<<5632, 256, 0, stream>>>(query, conv_w, conv_b, values, Wv,
                                          keys, bern, pad, cau,
                                          qcb, vtb, pmax, psum, maskf);
    ksm_final_kernel<<<BB * HH * NCH, 256, 0, stream>>>(keys, bern, pmax, psum, ksb);
    attn_mfma_kernel<<<BB * HH * 8, 512, 0, stream>>>(qcb, ksb, vtb, maskf, outp);
}

// Round 10
// 84.128 us; speedup vs baseline: 1.5570x; 1.0125x over previous
//
#include <hip/hip_runtime.h>
#include <hip/hip_bf16.h>
#include <math.h>

#define BB 4
#define LL 1024
#define EE 1024
#define HH 16
#define DD 64
#define NCH 8
#define CHROWS 128   // LL / NCH
#define K2C 0.04508422002777998f   // log2(e)/32
#define BIASC 7.2134752044448f     // 160 * K2C : fixed softmax bias

typedef __attribute__((ext_vector_type(8))) short short8;
typedef __attribute__((ext_vector_type(16))) float f32x16;
typedef __attribute__((ext_vector_type(4))) int int4v;

static __device__ __forceinline__ unsigned short bfbits(float x) {
    __hip_bfloat16 h = __float2bfloat16(x);
    return *(unsigned short*)&h;
}

#define CVTPK(dst, lo_, hi_) \
    asm("v_cvt_pk_bf16_f32 %0, %1, %2" : "=v"(dst) : "v"(lo_), "v"(hi_))
#define PLSWAP(x_, y_) \
    asm("v_permlane32_swap_b32 %0, %1" : "+v"(x_), "+v"(y_))

// ---------------------------------------------------------------------------
// Kernel 1 (fused prep): block-range dispatch
//   [0, 4096)    : grouped 3x3 conv -> bf16 qcb[bh][l][d]
//   [4096, 5120) : value linear -> transposed bf16 vt[bh][d][l]
//   [5120, 5632) : keys column-softmax chunk partials (+ maskf for h==0)
// ---------------------------------------------------------------------------
__global__ __launch_bounds__(256) void prep_kernel(
    const float* __restrict__ query,
    const float* __restrict__ conv_w,
    const float* __restrict__ conv_b,
    const float* __restrict__ values,
    const float* __restrict__ Wv,
    const float* __restrict__ keys,
    const int* __restrict__ bern,
    const int* __restrict__ pad,
    const int* __restrict__ cau,
    __hip_bfloat16* __restrict__ qcb,
    __hip_bfloat16* __restrict__ vt,
    float* __restrict__ pmax,
    float* __restrict__ psum,
    float* __restrict__ maskf) {
    __shared__ __align__(16) char SM[34048];
    int tid = threadIdx.x;
    int bid = blockIdx.x;

    if (bid < 4096) {
        // ---------------- conv ----------------
        int d = tid & 63;
        int lr = tid >> 6;
        int l0 = (bid & (LL / 4 - 1)) << 2;
        int bh = bid >> 8;
        int h = bh & (HH - 1);
        int b = bh >> 4;
        int l = l0 + lr;

        const float* w = conv_w + h * 9;
        float acc = conv_b[h];
        const float* qin = query + ((size_t)b * LL) * EE + h * DD;
        #pragma unroll
        for (int i = 0; i < 3; ++i) {
            int li = l + i - 1;
            if (li < 0 || li >= LL) continue;
            #pragma unroll
            for (int j = 0; j < 3; ++j) {
                int dj = d + j - 1;
                if (dj < 0 || dj >= DD) continue;
                acc += w[i * 3 + j] * qin[(size_t)li * EE + dj];
            }
        }
        qcb[((size_t)bh * LL + l) * DD + d] = __float2bfloat16(acc);
    } else if (bid < 5120) {
        // ---------------- vlin ----------------
        float (*WvS)[65] = (float(*)[65])SM;            // 16640 B
        float (*vs)[68]  = (float(*)[68])(SM + 16640);  // 17408 B
        int tile = bid - 4096;
        int lt = tile & 15;
        int bh = tile >> 4;
        int h = bh & (HH - 1);
        int b = bh >> 4;
        int l0 = lt * 64;

        for (int idx = tid; idx < 64 * 64; idx += 256)
            WvS[idx >> 6][idx & 63] = Wv[idx];
        const float* vin = values + ((size_t)b * LL + l0) * EE + h * DD;
        for (int idx = tid; idx < 1024; idx += 256) {
            int r = idx >> 4;
            int c4 = (idx & 15) << 2;
            *(float4*)&vs[r][c4] = *(const float4*)&vin[(size_t)r * EE + c4];
        }
        __syncthreads();

        int d = tid & 63;
        int r0 = (tid >> 6) * 16;
        float acc[16];
        #pragma unroll
        for (int r = 0; r < 16; ++r) acc[r] = 0.f;
        for (int k = 0; k < 64; ++k) {
            float wv = WvS[d][k];
            #pragma unroll
            for (int r = 0; r < 16; ++r) acc[r] += vs[r0 + r][k] * wv;
        }
        union { unsigned short us[16]; uint4 v[2]; } pk;
        #pragma unroll
        for (int r = 0; r < 16; ++r) pk.us[r] = bfbits(acc[r]);
        __hip_bfloat16* vo = vt + ((size_t)bh * DD + d) * LL + l0 + r0;
        *(uint4*)&vo[0] = pk.v[0];
        *(uint4*)&vo[8] = pk.v[1];
    } else {
        // ---------------- ksm_partial ----------------
        float (*sm)[64] = (float(*)[64])SM;
        float (*ss)[64] = (float(*)[64])(SM + 1024);
        int blk = bid - 5120;
        int d = tid & 63;
        int seg = tid >> 6;
        int ch = blk & (NCH - 1);
        int bh = blk >> 3;
        int h = bh & (HH - 1);
        int b = bh >> 4;
        int r0 = ch * CHROWS + seg * 32;

        if (h == 0 && tid < CHROWS) {
            int l = ch * CHROWS + tid;
            maskf[b * LL + l] = ((pad[b * LL + l] != 0) & (cau[b * LL + l] != 0)) ? -1e20f : 0.f;
        }

        const float* kin = keys + ((size_t)b * LL + r0) * EE + h * DD + d;
        const int* bm = bern + (size_t)bh * LL + r0;

        float v[32];
        #pragma unroll
        for (int i = 0; i < 32; ++i) v[i] = kin[(size_t)i * EE];
        float m = -INFINITY;
        #pragma unroll
        for (int i = 0; i < 32; ++i)
            if (bm[i]) m = fmaxf(m, v[i]);
        float s = 0.f;
        #pragma unroll
        for (int i = 0; i < 32; ++i)
            if (bm[i]) s += __expf(v[i] - m);

        sm[seg][d] = m;
        ss[seg][d] = s;
        __syncthreads();
        if (seg == 0) {
            float M = sm[0][d];
            #pragma unroll
            for (int t = 1; t < 4; ++t) M = fmaxf(M, sm[t][d]);
            float S = 0.f;
            if (M > -INFINITY) {
                #pragma unroll
                for (int t = 0; t < 4; ++t)
                    if (sm[t][d] > -INFINITY) S += ss[t][d] * __expf(sm[t][d] - M);
            }
            pmax[(size_t)blk * 64 + d] = M;
            psum[(size_t)blk * 64 + d] = S;
        }
    }
}

// ---------------------------------------------------------------------------
// Kernel 2: combine chunk partials; normalize chunk; write bf16 ksb.
// ---------------------------------------------------------------------------
__global__ __launch_bounds__(256) void ksm_final_kernel(
    const float* __restrict__ keys,
    const int* __restrict__ bern,
    const float* __restrict__ pmax,
    const float* __restrict__ psum,
    __hip_bfloat16* __restrict__ ksb) {
    int tid = threadIdx.x;
    int d = tid & 63;
    int seg = tid >> 6;
    int blk = blockIdx.x;
    int ch = blk & (NCH - 1);
    int bh = blk >> 3;
    int h = bh & (HH - 1);
    int b = bh >> 4;
    int r0 = ch * CHROWS + seg * 32;

    const float* pm = pmax + (size_t)bh * NCH * 64;
    const float* ps = psum + (size_t)bh * NCH * 64;
    float M = -INFINITY;
    #pragma unroll
    for (int c = 0; c < NCH; ++c) M = fmaxf(M, pm[c * 64 + d]);
    float S = 0.f;
    #pragma unroll
    for (int c = 0; c < NCH; ++c) {
        float mi = pm[c * 64 + d];
        if (mi > -INFINITY) S += ps[c * 64 + d] * __expf(mi - M);
    }
    float inv = 1.f / S;

    const float* kin = keys + ((size_t)b * LL + r0) * EE + h * DD + d;
    const int* bm = bern + (size_t)bh * LL + r0;
    __hip_bfloat16* kout = ksb + ((size_t)bh * LL + r0) * DD + d;
    #pragma unroll
    for (int i = 0; i < 32; ++i) {
        float val = bm[i] ? __expf(kin[(size_t)i * EE] - M) * inv : 0.f;
        kout[(size_t)i * DD] = __float2bfloat16(val);
    }
}

// ---------------------------------------------------------------------------
// Kernel 3: swapped-QK^T MFMA flash attention, fixed-bias softmax,
// 3-SLOT PIPELINE with COUNTED vmcnt + raw s_barrier (T3+T4):
//   per step: {vmcnt(4); s_barrier} -> issue tile kt+2 -> compute tile kt.
// Loads stay in flight across 2 steps; NEVER drained to 0 in the loop.
// Mask staged to LDS once (ds_read domain, keeps vmcnt count exact).
// 4 waves x 32 q-rows; 512 independent blocks; LDS 52KB -> 3 blocks/CU.
// ---------------------------------------------------------------------------
__global__ __launch_bounds__(256) void attn_mfma_kernel(
    const __hip_bfloat16* __restrict__ qcb,
    const __hip_bfloat16* __restrict__ ksb,
    const __hip_bfloat16* __restrict__ vtb,
    const float* __restrict__ maskf,
    float* __restrict__ out) {
    __shared__ __align__(16) char SMEM[53248];
    // K slots:  SMEM + slot*8192          (3 x 8KB)
    // V slots:  SMEM + 24576 + slot*8192  (3 x 8KB)
    // maskS:    SMEM + 49152              (4KB, 1024 floats)

    int tid = threadIdx.x;
    int lane = tid & 63;
    int w = tid >> 6;                  // 4 waves
    int q5 = lane & 31;
    int hi = lane >> 5;

    // XCD swizzle: 512 blocks; 64 consecutive swz per XCD -> 8 bh in its L2
    int bid = blockIdx.x;
    int swz = (bid & 7) * 64 + (bid >> 3);
    int bh = swz >> 3;
    int qb = swz & 7;
    int b = bh >> 4;
    int h = bh & 15;
    int q0w = qb * 128 + w * 32;

    // staging geometry: 256 threads x 2 its = 64 rows x 8 chunks of 8 bf16
    int srow = tid >> 3;               // 0..31 (it adds +32; (row&7) unchanged)
    int sch = tid & 7;
    int ssw = (sch ^ (srow & 7)) << 3;
    const short* kg = (const short*)ksb + (size_t)bh * LL * DD + (size_t)srow * DD + ssw;
    const short* vg = (const short*)vtb + (size_t)bh * DD * LL + (size_t)srow * LL + ssw;

    short8 Qf[4];
    {
        const short* qrow = (const short*)qcb + ((size_t)bh * LL + q0w + q5) * DD + 8 * hi;
        #pragma unroll
        for (int i = 0; i < 4; ++i)
            Qf[i] = *(const short8*)(qrow + 16 * i);
    }

    // ---- prologue: mask (1 load/thread) + tiles 0,1 (8 loads/thread) ----
    __builtin_amdgcn_global_load_lds(
        (const __attribute__((address_space(1))) void*)(maskf + b * LL + tid * 4),
        (__attribute__((address_space(3))) void*)(SMEM + 49152 + (w * 64) * 16), 16, 0, 0);
    #pragma unroll
    for (int t = 0; t < 2; ++t) {
        #pragma unroll
        for (int it = 0; it < 2; ++it) {
            __builtin_amdgcn_global_load_lds(
                (const __attribute__((address_space(1))) void*)(kg + (size_t)(t * 64 + it * 32) * DD),
                (__attribute__((address_space(3))) void*)(SMEM + t * 8192 + it * 4096 + w * 1024), 16, 0, 0);
            __builtin_amdgcn_global_load_lds(
                (const __attribute__((address_space(1))) void*)(vg + t * 64 + (size_t)it * 32 * LL),
                (__attribute__((address_space(3))) void*)(SMEM + 24576 + t * 8192 + it * 4096 + w * 1024), 16, 0, 0);
        }
    }

    f32x16 O0, O1;
    #pragma unroll
    for (int e = 0; e < 16; ++e) { O0[e] = 0.f; O1[e] = 0.f; }
    float lrun = 0.f;
    const float* mskS = (const float*)(SMEM + 49152);

    for (int kt = 0; kt < 16; ++kt) {
        // counted wait + raw barrier: tile kt's loads (older than the 4 issued
        // last step) are complete; last step's 4 stay in flight.
        if (kt < 15) {
            asm volatile("s_waitcnt vmcnt(4)\n\ts_barrier" ::: "memory");
        } else {
            asm volatile("s_waitcnt vmcnt(0)\n\ts_barrier" ::: "memory");
        }

        // issue prefetch for tile kt+2 into slot (kt+2)%3  (== slot (kt-1)%3,
        // whose readers all passed the barrier above)
        if (kt <= 13) {
            int tl = kt + 2;
            int sl = tl % 3;
            #pragma unroll
            for (int it = 0; it < 2; ++it) {
                __builtin_amdgcn_global_load_lds(
                    (const __attribute__((address_space(1))) void*)(kg + (size_t)(tl * 64 + it * 32) * DD),
                    (__attribute__((address_space(3))) void*)(SMEM + sl * 8192 + it * 4096 + w * 1024), 16, 0, 0);
                __builtin_amdgcn_global_load_lds(
                    (const __attribute__((address_space(1))) void*)(vg + tl * 64 + (size_t)it * 32 * LL),
                    (__attribute__((address_space(3))) void*)(SMEM + 24576 + sl * 8192 + it * 4096 + w * 1024), 16, 0, 0);
            }
        }

        int slot = kt % 3;
        int k0 = kt * 64;
        const short* Kb = (const short*)(SMEM + slot * 8192);
        const short* Vb = (const short*)(SMEM + 24576 + slot * 8192);
        int rsw = q5 & 7;

        // hoisted: K frags, V frags (LDS, swizzled), mask float4s (LDS)
        short8 Ka0[4], Ka1[4], Va0[4], Va1[4];
        #pragma unroll
        for (int i = 0; i < 4; ++i) {
            int off = ((2 * i + hi) ^ rsw) << 3;
            Ka0[i] = *(const short8*)&Kb[q5 * 64 + off];
            Ka1[i] = *(const short8*)&Kb[(32 + q5) * 64 + off];
            Va0[i] = *(const short8*)&Vb[q5 * 64 + off];
            Va1[i] = *(const short8*)&Vb[(32 + q5) * 64 + off];
        }
        float4 mk0[4], mk1[4];
        #pragma unroll
        for (int a = 0; a < 4; ++a) {
            mk0[a] = *(const float4*)&mskS[k0 + 8 * a + 4 * hi];
            mk1[a] = *(const float4*)&mskS[k0 + 32 + 8 * a + 4 * hi];
        }

        f32x16 S0, S1;
        #pragma unroll
        for (int e = 0; e < 16; ++e) { S0[e] = 0.f; S1[e] = 0.f; }
        __builtin_amdgcn_s_setprio(1);
        #pragma unroll
        for (int i = 0; i < 4; ++i) {
            S0 = __builtin_amdgcn_mfma_f32_32x32x16_bf16(Ka0[i], Qf[i], S0, 0, 0, 0);
            S1 = __builtin_amdgcn_mfma_f32_32x32x16_bf16(Ka1[i], Qf[i], S1, 0, 0, 0);
        }
        __builtin_amdgcn_s_setprio(0);

        // fixed-bias softmax: pv = exp2(S*K2C + (mask*K2C - BIASC))
        float pv[32];
        #pragma unroll
        for (int a = 0; a < 4; ++a) {
            #pragma unroll
            for (int jj = 0; jj < 4; ++jj) {
                float ma0 = __builtin_fmaf(mk0[a][jj], K2C, -BIASC);
                float ma1 = __builtin_fmaf(mk1[a][jj], K2C, -BIASC);
                pv[4 * a + jj]      = exp2f(__builtin_fmaf(S0[4 * a + jj], K2C, ma0));
                pv[16 + 4 * a + jj] = exp2f(__builtin_fmaf(S1[4 * a + jj], K2C, ma1));
            }
        }

        float t16[16];
        #pragma unroll
        for (int r = 0; r < 16; ++r) t16[r] = pv[r] + pv[r + 16];
        float t8[8];
        #pragma unroll
        for (int r = 0; r < 8; ++r) t8[r] = t16[r] + t16[r + 8];
        float rs = ((t8[0] + t8[1]) + (t8[2] + t8[3])) + ((t8[4] + t8[5]) + (t8[6] + t8[7]));
        rs += __shfl_xor(rs, 32, 64);
        lrun += rs;

        // pack P -> B-fragments via cvt_pk + permlane32_swap
        union PW { int4v i4; short8 s8; } pa[4];
        #pragma unroll
        for (int st = 0; st < 2; ++st) {
            int c0, d0, c1, d1, c2, d2, c3, d3;
            CVTPK(c0, pv[16 * st + 0], pv[16 * st + 1]);
            CVTPK(d0, pv[16 * st + 4], pv[16 * st + 5]);
            PLSWAP(c0, d0);
            CVTPK(c1, pv[16 * st + 2], pv[16 * st + 3]);
            CVTPK(d1, pv[16 * st + 6], pv[16 * st + 7]);
            PLSWAP(c1, d1);
            pa[2 * st].i4 = (int4v){c0, c1, d0, d1};
            CVTPK(c2, pv[16 * st + 8], pv[16 * st + 9]);
            CVTPK(d2, pv[16 * st + 12], pv[16 * st + 13]);
            PLSWAP(c2, d2);
            CVTPK(c3, pv[16 * st + 10], pv[16 * st + 11]);
            CVTPK(d3, pv[16 * st + 14], pv[16 * st + 15]);
            PLSWAP(c3, d3);
            pa[2 * st + 1].i4 = (int4v){c2, c3, d2, d3};
        }

        __builtin_amdgcn_s_setprio(1);
        #pragma unroll
        for (int ks = 0; ks < 4; ++ks) {
            O0 = __builtin_amdgcn_mfma_f32_32x32x16_bf16(Va0[ks], pa[ks].s8, O0, 0, 0, 0);
            O1 = __builtin_amdgcn_mfma_f32_32x32x16_bf16(Va1[ks], pa[ks].s8, O1, 0, 0, 0);
        }
        __builtin_amdgcn_s_setprio(0);
    }

    // epilogue: full barrier once, then alias OutS over the K/V slots
    __syncthreads();
    float invl = 1.f / lrun;
    float* oreg = (float*)SMEM + w * (32 * 36);   // 4 x 4608B = 18432B
    int orow = lane >> 1;
    int ocol = (lane & 1) * 16;

    #pragma unroll
    for (int r = 0; r < 16; ++r) {
        int dl = (r & 3) + 8 * (r >> 2) + 4 * hi;
        oreg[q5 * 36 + dl] = O0[r];
    }
    if (hi == 0) oreg[q5 * 36 + 32] = invl;
    asm volatile("" ::: "memory");
    {
        float iv = oreg[orow * 36 + 32];
        float* gout = out + ((size_t)b * LL + q0w + orow) * EE + h * DD + ocol;
        #pragma unroll
        for (int c = 0; c < 4; ++c) {
            float4 vv = *(float4*)&oreg[orow * 36 + ocol + 4 * c];
            vv.x *= iv; vv.y *= iv; vv.z *= iv; vv.w *= iv;
            *(float4*)&gout[4 * c] = vv;
        }
    }
    asm volatile("" ::: "memory");
    #pragma unroll
    for (int r = 0; r < 16; ++r) {
        int dl = (r & 3) + 8 * (r >> 2) + 4 * hi;
        oreg[q5 * 36 + dl] = O1[r];
    }
    asm volatile("" ::: "memory");
    {
        float iv = oreg[orow * 36 + 32];
        float* gout = out + ((size_t)b * LL + q0w + orow) * EE + h * DD + 32 + ocol;
        #pragma unroll
        for (int c = 0; c < 4; ++c) {
            float4 vv = *(float4*)&oreg[orow * 36 + ocol + 4 * c];
            vv.x *= iv; vv.y *= iv; vv.z *= iv; vv.w *= iv;
            *(float4*)&gout[4 * c] = vv;
        }
    }
}

extern "C" void kernel_launch(void* const* d_in, const int* in_sizes, int n_in,
                              void* d_out, int out_size, void* d_ws, size_t ws_size,
                              hipStream_t stream) {
    const float* query = (const float*)d_in[0];
    const float* keys  = (const float*)d_in[1];
    const float* values = (const float*)d_in[2];
    const int* pad  = (const int*)d_in[3];
    const int* cau  = (const int*)d_in[4];
    const int* bern = (const int*)d_in[5];
    const float* conv_w = (const float*)d_in[6];
    const float* conv_b = (const float*)d_in[7];
    const float* Wv = (const float*)d_in[8];
    float* outp = (float*)d_out;

    const size_t per = (size_t)BB * HH * LL * DD;
    __hip_bfloat16* qcb = (__hip_bfloat16*)d_ws;
    __hip_bfloat16* ksb = qcb + per;
    __hip_bfloat16* vtb = ksb + per;
    float* pmax = (float*)(vtb + per);
    float* psum = pmax + (size_t)BB * HH * NCH * 64;
    float* maskf = psum + (size_t)BB * HH * NCH * 64;

    prep_kernel<<<5632, 256, 0, stream>>>(query, conv_w, conv_b, values, Wv,
                                          keys, bern, pad, cau,
                                          qcb, vtb, pmax, psum, maskf);
    ksm_final_kernel<<<BB * HH * NCH, 256, 0, stream>>>(keys, bern, pmax, psum, ksb);
    attn_mfma_kernel<<<BB * HH * 8, 256, 0, stream>>>(qcb, ksb, vtb, maskf, outp);
}

// Round 11
// 76.858 us; speedup vs baseline: 1.7043x; 1.0946x over previous
//
#include <hip/hip_runtime.h>
#include <hip/hip_bf16.h>
#include <math.h>

#define BB 4
#define LL 1024
#define EE 1024
#define HH 16
#define DD 64
#define NCH 8
#define CHROWS 128   // LL / NCH
#define K2C 0.04508422002777998f   // log2(e)/32
#define BIASC 7.2134752044448f     // 160 * K2C : fixed softmax bias

typedef __attribute__((ext_vector_type(8))) short short8;
typedef __attribute__((ext_vector_type(4))) float f32x4;
typedef __attribute__((ext_vector_type(4))) int int4v;

static __device__ __forceinline__ unsigned short bfbits(float x) {
    __hip_bfloat16 h = __float2bfloat16(x);
    return *(unsigned short*)&h;
}

#define CVTPK(dst, lo_, hi_) \
    asm("v_cvt_pk_bf16_f32 %0, %1, %2" : "=v"(dst) : "v"(lo_), "v"(hi_))

// ---------------------------------------------------------------------------
// Kernel 1 (fused prep): block-range dispatch
//   [0, 4096)    : grouped 3x3 conv -> bf16 qcb[bh][l][d]
//   [4096, 5120) : value linear -> PERMUTED transposed bf16 vt[bh][d][l']
//                  (l' = within-32-block bit-rotate so PV B-frags are lane-local)
//   [5120, 5632) : keys column-softmax chunk partials (+ mbias for h==0:
//                  mbias[b][l] = mask ? -1e20*K2C-BIASC : -BIASC)
// ---------------------------------------------------------------------------
__global__ __launch_bounds__(256) void prep_kernel(
    const float* __restrict__ query,
    const float* __restrict__ conv_w,
    const float* __restrict__ conv_b,
    const float* __restrict__ values,
    const float* __restrict__ Wv,
    const float* __restrict__ keys,
    const int* __restrict__ bern,
    const int* __restrict__ pad,
    const int* __restrict__ cau,
    __hip_bfloat16* __restrict__ qcb,
    __hip_bfloat16* __restrict__ vt,
    float* __restrict__ pmax,
    float* __restrict__ psum,
    float* __restrict__ mbias) {
    __shared__ __align__(16) char SM[34048];
    int tid = threadIdx.x;
    int bid = blockIdx.x;

    if (bid < 4096) {
        // ---------------- conv ----------------
        int d = tid & 63;
        int lr = tid >> 6;
        int l0 = (bid & (LL / 4 - 1)) << 2;
        int bh = bid >> 8;
        int h = bh & (HH - 1);
        int b = bh >> 4;
        int l = l0 + lr;

        const float* w = conv_w + h * 9;
        float acc = conv_b[h];
        const float* qin = query + ((size_t)b * LL) * EE + h * DD;
        #pragma unroll
        for (int i = 0; i < 3; ++i) {
            int li = l + i - 1;
            if (li < 0 || li >= LL) continue;
            #pragma unroll
            for (int j = 0; j < 3; ++j) {
                int dj = d + j - 1;
                if (dj < 0 || dj >= DD) continue;
                acc += w[i * 3 + j] * qin[(size_t)li * EE + dj];
            }
        }
        qcb[((size_t)bh * LL + l) * DD + d] = __float2bfloat16(acc);
    } else if (bid < 5120) {
        // ---------------- vlin (permuted store) ----------------
        float (*WvS)[65] = (float(*)[65])SM;            // 16640 B
        float (*vs)[68]  = (float(*)[68])(SM + 16640);  // 17408 B
        int tile = bid - 4096;
        int lt = tile & 15;
        int bh = tile >> 4;
        int h = bh & (HH - 1);
        int b = bh >> 4;
        int l0 = lt * 64;

        for (int idx = tid; idx < 64 * 64; idx += 256)
            WvS[idx >> 6][idx & 63] = Wv[idx];
        const float* vin = values + ((size_t)b * LL + l0) * EE + h * DD;
        for (int idx = tid; idx < 1024; idx += 256) {
            int r = idx >> 4;
            int c4 = (idx & 15) << 2;
            *(float4*)&vs[r][c4] = *(const float4*)&vin[(size_t)r * EE + c4];
        }
        __syncthreads();

        int d = tid & 63;
        int r0 = (tid >> 6) * 16;
        float acc[16];
        #pragma unroll
        for (int r = 0; r < 16; ++r) acc[r] = 0.f;
        for (int k = 0; k < 64; ++k) {
            float wv = WvS[d][k];
            #pragma unroll
            for (int r = 0; r < 16; ++r) acc[r] += vs[r0 + r][k] * wv;
        }
        union { unsigned short us[16]; uint2 u2[4]; } pk;
        #pragma unroll
        for (int r = 0; r < 16; ++r) pk.us[r] = bfbits(acc[r]);
        // permuted write: row l0 + 32C + 4h4 + 8g2 + m  for acc idx 4g2+m
        int C32 = (r0 >> 5) << 5;        // 0 or 32
        int h4 = (r0 >> 4) & 1;          // selects the +4 slot
        __hip_bfloat16* vo = vt + ((size_t)bh * DD + d) * LL + l0 + C32 + 4 * h4;
        #pragma unroll
        for (int g2 = 0; g2 < 4; ++g2)
            *(uint2*)&vo[8 * g2] = pk.u2[g2];
    } else {
        // ---------------- ksm_partial (+ mbias) ----------------
        float (*sm)[64] = (float(*)[64])SM;
        float (*ss)[64] = (float(*)[64])(SM + 1024);
        int blk = bid - 5120;
        int d = tid & 63;
        int seg = tid >> 6;
        int ch = blk & (NCH - 1);
        int bh = blk >> 3;
        int h = bh & (HH - 1);
        int b = bh >> 4;
        int r0 = ch * CHROWS + seg * 32;

        if (h == 0 && tid < CHROWS) {
            int l = ch * CHROWS + tid;
            int msk = (pad[b * LL + l] != 0) & (cau[b * LL + l] != 0);
            mbias[b * LL + l] = msk ? (-1e20f * K2C - BIASC) : -BIASC;
        }

        const float* kin = keys + ((size_t)b * LL + r0) * EE + h * DD + d;
        const int* bm = bern + (size_t)bh * LL + r0;

        float v[32];
        #pragma unroll
        for (int i = 0; i < 32; ++i) v[i] = kin[(size_t)i * EE];
        float m = -INFINITY;
        #pragma unroll
        for (int i = 0; i < 32; ++i)
            if (bm[i]) m = fmaxf(m, v[i]);
        float s = 0.f;
        #pragma unroll
        for (int i = 0; i < 32; ++i)
            if (bm[i]) s += __expf(v[i] - m);

        sm[seg][d] = m;
        ss[seg][d] = s;
        __syncthreads();
        if (seg == 0) {
            float M = sm[0][d];
            #pragma unroll
            for (int t = 1; t < 4; ++t) M = fmaxf(M, sm[t][d]);
            float S = 0.f;
            if (M > -INFINITY) {
                #pragma unroll
                for (int t = 0; t < 4; ++t)
                    if (sm[t][d] > -INFINITY) S += ss[t][d] * __expf(sm[t][d] - M);
            }
            pmax[(size_t)blk * 64 + d] = M;
            psum[(size_t)blk * 64 + d] = S;
        }
    }
}

// ---------------------------------------------------------------------------
// Kernel 2: combine chunk partials; normalize chunk; write bf16 ksb.
// ---------------------------------------------------------------------------
__global__ __launch_bounds__(256) void ksm_final_kernel(
    const float* __restrict__ keys,
    const int* __restrict__ bern,
    const float* __restrict__ pmax,
    const float* __restrict__ psum,
    __hip_bfloat16* __restrict__ ksb) {
    int tid = threadIdx.x;
    int d = tid & 63;
    int seg = tid >> 6;
    int blk = blockIdx.x;
    int ch = blk & (NCH - 1);
    int bh = blk >> 3;
    int h = bh & (HH - 1);
    int b = bh >> 4;
    int r0 = ch * CHROWS + seg * 32;

    const float* pm = pmax + (size_t)bh * NCH * 64;
    const float* ps = psum + (size_t)bh * NCH * 64;
    float M = -INFINITY;
    #pragma unroll
    for (int c = 0; c < NCH; ++c) M = fmaxf(M, pm[c * 64 + d]);
    float S = 0.f;
    #pragma unroll
    for (int c = 0; c < NCH; ++c) {
        float mi = pm[c * 64 + d];
        if (mi > -INFINITY) S += ps[c * 64 + d] * __expf(mi - M);
    }
    float inv = 1.f / S;

    const float* kin = keys + ((size_t)b * LL + r0) * EE + h * DD + d;
    const int* bm = bern + (size_t)bh * LL + r0;
    __hip_bfloat16* kout = ksb + ((size_t)bh * LL + r0) * DD + d;
    #pragma unroll
    for (int i = 0; i < 32; ++i) {
        float val = bm[i] ? __expf(kin[(size_t)i * EE] - M) * inv : 0.f;
        kout[(size_t)i * DD] = __float2bfloat16(val);
    }
}

// ---------------------------------------------------------------------------
// Kernel 3: swapped-QK^T flash attention on 16x16x32 MFMA.
// 16 q-rows/wave, 4 waves/block (64 q), 1024 independent blocks
// (4 blocks/CU, 4 waves/SIMD). Fixed-bias softmax; permuted-V makes PV
// B-fragments lane-local (8 cvt_pk, no permlane, no P LDS); direct
// coalesced epilogue stores (no LDS transpose). KVBLK=64 double-buffered.
// ---------------------------------------------------------------------------
__global__ __launch_bounds__(256) void attn_mfma_kernel(
    const __hip_bfloat16* __restrict__ qcb,
    const __hip_bfloat16* __restrict__ ksb,
    const __hip_bfloat16* __restrict__ vtb,
    const float* __restrict__ mbias,
    float* __restrict__ out) {
    __shared__ __align__(16) short KsS[2][4096];   // 16 KB
    __shared__ __align__(16) short VtS[2][4096];   // 16 KB
    __shared__ __align__(16) float mskS[1024];     // 4 KB

    int tid = threadIdx.x;
    int lane = tid & 63;
    int w = tid >> 6;                  // 4 waves
    int q15 = lane & 15;
    int g = (lane >> 4) & 3;

    // XCD swizzle: 1024 blocks; 128 consecutive swz per XCD -> 8 bh per L2
    int bid = blockIdx.x;
    int swz = (bid & 7) * 128 + (bid >> 3);
    int bh = swz >> 4;
    int qb = swz & 15;
    int b = bh >> 4;
    int h = bh & 15;
    int q0w = qb * 64 + w * 16;

    // staging geometry: 256 threads x 2 its = 64 rows x 8 chunks of 8 bf16
    int srow = tid >> 3;
    int sch = tid & 7;
    int ssw = (sch ^ (srow & 7)) << 3;
    const short* kg = (const short*)ksb + (size_t)bh * LL * DD + (size_t)srow * DD + ssw;
    const short* vg = (const short*)vtb + (size_t)bh * DD * LL + (size_t)srow * LL + ssw;

    // Q fragments (B-operand): lane supplies Q[q0w+q15][8g+32c+j]
    short8 Qf0, Qf1;
    {
        const short* qrow = (const short*)qcb + ((size_t)bh * LL + q0w + q15) * DD + 8 * g;
        Qf0 = *(const short8*)(qrow);
        Qf1 = *(const short8*)(qrow + 32);
    }

    // prologue: mask bias (1 load/thread) + tile 0 (4 loads/thread)
    __builtin_amdgcn_global_load_lds(
        (const __attribute__((address_space(1))) void*)(mbias + b * LL + tid * 4),
        (__attribute__((address_space(3))) void*)&mskS[w * 256], 16, 0, 0);
    #pragma unroll
    for (int it = 0; it < 2; ++it) {
        __builtin_amdgcn_global_load_lds(
            (const __attribute__((address_space(1))) void*)(kg + (size_t)(it * 32) * DD),
            (__attribute__((address_space(3))) void*)&KsS[0][(it * 4 + w) * 512], 16, 0, 0);
        __builtin_amdgcn_global_load_lds(
            (const __attribute__((address_space(1))) void*)(vg + (size_t)it * 32 * LL),
            (__attribute__((address_space(3))) void*)&VtS[0][(it * 4 + w) * 512], 16, 0, 0);
    }

    f32x4 O[4];
    #pragma unroll
    for (int u = 0; u < 4; ++u) O[u] = (f32x4){0.f, 0.f, 0.f, 0.f};
    float lsum = 0.f;

    for (int kt = 0; kt < 16; ++kt) {
        __syncthreads();   // tile kt ready; all waves done with other slot

        if (kt < 15) {
            int nb = (kt + 1) & 1;
            int k0n = (kt + 1) * 64;
            #pragma unroll
            for (int it = 0; it < 2; ++it) {
                __builtin_amdgcn_global_load_lds(
                    (const __attribute__((address_space(1))) void*)(kg + (size_t)(k0n + it * 32) * DD),
                    (__attribute__((address_space(3))) void*)&KsS[nb][(it * 4 + w) * 512], 16, 0, 0);
                __builtin_amdgcn_global_load_lds(
                    (const __attribute__((address_space(1))) void*)(vg + k0n + (size_t)it * 32 * LL),
                    (__attribute__((address_space(3))) void*)&VtS[nb][(it * 4 + w) * 512], 16, 0, 0);
            }
        }

        int cb = kt & 1;
        int k0 = kt * 64;
        const short* Kb = KsS[cb];
        const short* Vb = VtS[cb];
        int sw = q15 & 7;
        int off0 = (g ^ sw) << 3;
        int off1 = ((g + 4) ^ sw) << 3;

        // S^T tiles: S[t] = K-subtile(16 kv) x Q  (K=64 via 2 mfma)
        f32x4 S[4];
        __builtin_amdgcn_s_setprio(1);
        #pragma unroll
        for (int t = 0; t < 4; ++t) {
            short8 kf0 = *(const short8*)&Kb[(16 * t + q15) * 64 + off0];
            short8 kf1 = *(const short8*)&Kb[(16 * t + q15) * 64 + off1];
            f32x4 z = (f32x4){0.f, 0.f, 0.f, 0.f};
            z = __builtin_amdgcn_mfma_f32_16x16x32_bf16(kf0, Qf0, z, 0, 0, 0);
            S[t] = __builtin_amdgcn_mfma_f32_16x16x32_bf16(kf1, Qf1, z, 0, 0, 0);
        }
        __builtin_amdgcn_s_setprio(0);

        // fixed-bias softmax: pv = exp2(S*K2C + mbias)   (masked -> exact 0)
        float4 mb[4];
        #pragma unroll
        for (int t = 0; t < 4; ++t)
            mb[t] = *(const float4*)&mskS[k0 + 16 * t + 4 * g];
        float pv[4][4];
        #pragma unroll
        for (int t = 0; t < 4; ++t)
            #pragma unroll
            for (int r = 0; r < 4; ++r)
                pv[t][r] = exp2f(__builtin_fmaf(S[t][r], K2C, mb[t][r]));

        float s0 = (pv[0][0] + pv[0][1]) + (pv[0][2] + pv[0][3]);
        float s1 = (pv[1][0] + pv[1][1]) + (pv[1][2] + pv[1][3]);
        float s2 = (pv[2][0] + pv[2][1]) + (pv[2][2] + pv[2][3]);
        float s3 = (pv[3][0] + pv[3][1]) + (pv[3][2] + pv[3][3]);
        lsum += (s0 + s1) + (s2 + s3);

        // pack P -> lane-local B-fragments (permuted-V: no cross-lane moves)
        int4v pa0, pa1;
        {
            int d0, d1, d2, d3;
            CVTPK(d0, pv[0][0], pv[0][1]);
            CVTPK(d1, pv[0][2], pv[0][3]);
            CVTPK(d2, pv[1][0], pv[1][1]);
            CVTPK(d3, pv[1][2], pv[1][3]);
            pa0 = (int4v){d0, d1, d2, d3};
            CVTPK(d0, pv[2][0], pv[2][1]);
            CVTPK(d1, pv[2][2], pv[2][3]);
            CVTPK(d2, pv[3][0], pv[3][1]);
            CVTPK(d3, pv[3][2], pv[3][3]);
            pa1 = (int4v){d0, d1, d2, d3};
        }
        union PW { int4v i4; short8 s8; } pw0, pw1;
        pw0.i4 = pa0;
        pw1.i4 = pa1;

        // O^T tiles: O[u](16 d x 16 q) += V^T-subtile x P
        __builtin_amdgcn_s_setprio(1);
        #pragma unroll
        for (int u = 0; u < 4; ++u) {
            short8 vf0 = *(const short8*)&Vb[(16 * u + q15) * 64 + off0];
            short8 vf1 = *(const short8*)&Vb[(16 * u + q15) * 64 + off1];
            O[u] = __builtin_amdgcn_mfma_f32_16x16x32_bf16(vf0, pw0.s8, O[u], 0, 0, 0);
            O[u] = __builtin_amdgcn_mfma_f32_16x16x32_bf16(vf1, pw1.s8, O[u], 0, 0, 0);
        }
        __builtin_amdgcn_s_setprio(0);
    }

    // epilogue: cross-lane lsum reduce (4 g-groups per q), direct stores
    lsum += __shfl_xor(lsum, 16, 64);
    lsum += __shfl_xor(lsum, 32, 64);
    float invl = 1.f / lsum;

    float* gout = out + ((size_t)b * LL + q0w + q15) * EE + h * DD + 4 * g;
    #pragma unroll
    for (int u = 0; u < 4; ++u) {
        float4 vv = { O[u][0] * invl, O[u][1] * invl, O[u][2] * invl, O[u][3] * invl };
        *(float4*)&gout[16 * u] = vv;
    }
}

extern "C" void kernel_launch(void* const* d_in, const int* in_sizes, int n_in,
                              void* d_out, int out_size, void* d_ws, size_t ws_size,
                              hipStream_t stream) {
    const float* query = (const float*)d_in[0];
    const float* keys  = (const float*)d_in[1];
    const float* values = (const float*)d_in[2];
    const int* pad  = (const int*)d_in[3];
    const int* cau  = (const int*)d_in[4];
    const int* bern = (const int*)d_in[5];
    const float* conv_w = (const float*)d_in[6];
    const float* conv_b = (const float*)d_in[7];
    const float* Wv = (const float*)d_in[8];
    float* outp = (float*)d_out;

    const size_t per = (size_t)BB * HH * LL * DD;
    __hip_bfloat16* qcb = (__hip_bfloat16*)d_ws;
    __hip_bfloat16* ksb = qcb + per;
    __hip_bfloat16* vtb = ksb + per;
    float* pmax = (float*)(vtb + per);
    float* psum = pmax + (size_t)BB * HH * NCH * 64;
    float* mbias = psum + (size_t)BB * HH * NCH * 64;

    prep_kernel<<<5632, 256, 0, stream>>>(query, conv_w, conv_b, values, Wv,
                                          keys, bern, pad, cau,
                                          qcb, vtb, pmax, psum, mbias);
    ksm_final_kernel<<<BB * HH * NCH, 256, 0, stream>>>(keys, bern, pmax, psum, ksb);
    attn_mfma_kernel<<<BB * HH * 16, 256, 0, stream>>>(qcb, ksb, vtb, mbias, outp);
}

// Round 12
// 74.667 us; speedup vs baseline: 1.7543x; 1.0293x over previous
//
#include <hip/hip_runtime.h>
#include <hip/hip_bf16.h>
#include <math.h>

#define BB 4
#define LL 1024
#define EE 1024
#define HH 16
#define DD 64
#define VROWS 80     // V padded: 64 data rows + ones-row(64) + 15 zero rows
#define NCH 8
#define CHROWS 128   // LL / NCH
#define K2C 0.04508422002777998f   // log2(e)/32, pre-folded into Q

typedef __attribute__((ext_vector_type(8))) short short8;
typedef __attribute__((ext_vector_type(4))) float f32x4;
typedef __attribute__((ext_vector_type(4))) int int4v;

static __device__ __forceinline__ unsigned short bfbits(float x) {
    __hip_bfloat16 h = __float2bfloat16(x);
    return *(unsigned short*)&h;
}

#define CVTPK(dst, lo_, hi_) \
    asm("v_cvt_pk_bf16_f32 %0, %1, %2" : "=v"(dst) : "v"(lo_), "v"(hi_))

// ---------------------------------------------------------------------------
// Kernel 1 (fused prep): block-range dispatch
//   [0, 4096)    : grouped 3x3 conv -> bf16 qcb[bh][l][d], PRE-SCALED by K2C
//   [4096, 5120) : value linear -> PERMUTED transposed bf16 vt[bh][80][l'],
//                  masked columns zeroed; row 64 = mask01 (permuted);
//                  rows 65..79 = 0.
//   [5120, 5632) : keys column-softmax chunk partials
// ---------------------------------------------------------------------------
__global__ __launch_bounds__(256) void prep_kernel(
    const float* __restrict__ query,
    const float* __restrict__ conv_w,
    const float* __restrict__ conv_b,
    const float* __restrict__ values,
    const float* __restrict__ Wv,
    const float* __restrict__ keys,
    const int* __restrict__ bern,
    const int* __restrict__ pad,
    const int* __restrict__ cau,
    __hip_bfloat16* __restrict__ qcb,
    __hip_bfloat16* __restrict__ vt,
    float* __restrict__ pmax,
    float* __restrict__ psum) {
    __shared__ __align__(16) char SM[34304];
    int tid = threadIdx.x;
    int bid = blockIdx.x;

    if (bid < 4096) {
        // ---------------- conv (Q pre-scaled by K2C) ----------------
        int d = tid & 63;
        int lr = tid >> 6;
        int l0 = (bid & (LL / 4 - 1)) << 2;
        int bh = bid >> 8;
        int h = bh & (HH - 1);
        int b = bh >> 4;
        int l = l0 + lr;

        const float* w = conv_w + h * 9;
        float acc = conv_b[h];
        const float* qin = query + ((size_t)b * LL) * EE + h * DD;
        #pragma unroll
        for (int i = 0; i < 3; ++i) {
            int li = l + i - 1;
            if (li < 0 || li >= LL) continue;
            #pragma unroll
            for (int j = 0; j < 3; ++j) {
                int dj = d + j - 1;
                if (dj < 0 || dj >= DD) continue;
                acc += w[i * 3 + j] * qin[(size_t)li * EE + dj];
            }
        }
        qcb[((size_t)bh * LL + l) * DD + d] = __float2bfloat16(acc * K2C);
    } else if (bid < 5120) {
        // ---------------- vlin (masked, permuted, +ones-row) ----------------
        float (*WvS)[65] = (float(*)[65])SM;            // 16640 B
        float (*vs)[68]  = (float(*)[68])(SM + 16640);  // 17408 B
        float* mS = (float*)(SM + 34048);               // 64 floats
        int tile = bid - 4096;
        int lt = tile & 15;
        int bh = tile >> 4;
        int h = bh & (HH - 1);
        int b = bh >> 4;
        int l0 = lt * 64;

        if (tid < 64) {
            int l = l0 + tid;
            mS[tid] = ((pad[b * LL + l] != 0) & (cau[b * LL + l] != 0)) ? 0.f : 1.f;
        }
        for (int idx = tid; idx < 64 * 64; idx += 256)
            WvS[idx >> 6][idx & 63] = Wv[idx];
        const float* vin = values + ((size_t)b * LL + l0) * EE + h * DD;
        for (int idx = tid; idx < 1024; idx += 256) {
            int r = idx >> 4;
            int c4 = (idx & 15) << 2;
            *(float4*)&vs[r][c4] = *(const float4*)&vin[(size_t)r * EE + c4];
        }
        __syncthreads();

        int d = tid & 63;
        int r0 = (tid >> 6) * 16;
        float acc[16];
        #pragma unroll
        for (int r = 0; r < 16; ++r) acc[r] = 0.f;
        for (int k = 0; k < 64; ++k) {
            float wv = WvS[d][k];
            #pragma unroll
            for (int r = 0; r < 16; ++r) acc[r] += vs[r0 + r][k] * wv;
        }
        #pragma unroll
        for (int r = 0; r < 16; ++r) acc[r] *= mS[r0 + r];   // zero masked columns
        union { unsigned short us[16]; uint2 u2[4]; } pk;
        #pragma unroll
        for (int r = 0; r < 16; ++r) pk.us[r] = bfbits(acc[r]);
        // permuted write: source l0+16a+4g2+m -> l0 + 32(a>>1) + 4(a&1) + 8g2 + m
        int a = tid >> 6;
        int C32 = (a >> 1) << 5;
        int h4 = a & 1;
        __hip_bfloat16* vo = vt + ((size_t)bh * VROWS + d) * LL + l0 + C32 + 4 * h4;
        #pragma unroll
        for (int g2 = 0; g2 < 4; ++g2)
            *(uint2*)&vo[8 * g2] = pk.u2[g2];

        // ones-row (row 64), same permutation; rows 65..79 zero
        if (tid < 64) {
            int aa = tid >> 4, g2 = (tid >> 2) & 3, m = tid & 3;
            int dst = l0 + 32 * (aa >> 1) + 4 * (aa & 1) + 8 * g2 + m;
            vt[((size_t)bh * VROWS + 64) * LL + dst] = __float2bfloat16(mS[tid]);
        }
        for (int idx = tid; idx < 15 * 64; idx += 256) {
            int rr = idx >> 6, l = idx & 63;
            vt[((size_t)bh * VROWS + 65 + rr) * LL + l0 + l] = __float2bfloat16(0.f);
        }
    } else {
        // ---------------- ksm_partial ----------------
        float (*sm)[64] = (float(*)[64])SM;
        float (*ss)[64] = (float(*)[64])(SM + 1024);
        int blk = bid - 5120;
        int d = tid & 63;
        int seg = tid >> 6;
        int ch = blk & (NCH - 1);
        int bh = blk >> 3;
        int h = bh & (HH - 1);
        int b = bh >> 4;
        int r0 = ch * CHROWS + seg * 32;

        const float* kin = keys + ((size_t)b * LL + r0) * EE + h * DD + d;
        const int* bm = bern + (size_t)bh * LL + r0;

        float v[32];
        #pragma unroll
        for (int i = 0; i < 32; ++i) v[i] = kin[(size_t)i * EE];
        float m = -INFINITY;
        #pragma unroll
        for (int i = 0; i < 32; ++i)
            if (bm[i]) m = fmaxf(m, v[i]);
        float s = 0.f;
        #pragma unroll
        for (int i = 0; i < 32; ++i)
            if (bm[i]) s += __expf(v[i] - m);

        sm[seg][d] = m;
        ss[seg][d] = s;
        __syncthreads();
        if (seg == 0) {
            float M = sm[0][d];
            #pragma unroll
            for (int t = 1; t < 4; ++t) M = fmaxf(M, sm[t][d]);
            float S = 0.f;
            if (M > -INFINITY) {
                #pragma unroll
                for (int t = 0; t < 4; ++t)
                    if (sm[t][d] > -INFINITY) S += ss[t][d] * __expf(sm[t][d] - M);
            }
            pmax[(size_t)blk * 64 + d] = M;
            psum[(size_t)blk * 64 + d] = S;
        }
    }
}

// ---------------------------------------------------------------------------
// Kernel 2: combine chunk partials; normalize chunk; write bf16 ksb.
// ---------------------------------------------------------------------------
__global__ __launch_bounds__(256) void ksm_final_kernel(
    const float* __restrict__ keys,
    const int* __restrict__ bern,
    const float* __restrict__ pmax,
    const float* __restrict__ psum,
    __hip_bfloat16* __restrict__ ksb) {
    int tid = threadIdx.x;
    int d = tid & 63;
    int seg = tid >> 6;
    int blk = blockIdx.x;
    int ch = blk & (NCH - 1);
    int bh = blk >> 3;
    int h = bh & (HH - 1);
    int b = bh >> 4;
    int r0 = ch * CHROWS + seg * 32;

    const float* pm = pmax + (size_t)bh * NCH * 64;
    const float* ps = psum + (size_t)bh * NCH * 64;
    float M = -INFINITY;
    #pragma unroll
    for (int c = 0; c < NCH; ++c) M = fmaxf(M, pm[c * 64 + d]);
    float S = 0.f;
    #pragma unroll
    for (int c = 0; c < NCH; ++c) {
        float mi = pm[c * 64 + d];
        if (mi > -INFINITY) S += ps[c * 64 + d] * __expf(mi - M);
    }
    float inv = 1.f / S;

    const float* kin = keys + ((size_t)b * LL + r0) * EE + h * DD + d;
    const int* bm = bern + (size_t)bh * LL + r0;
    __hip_bfloat16* kout = ksb + ((size_t)bh * LL + r0) * DD + d;
    #pragma unroll
    for (int i = 0; i < 32; ++i) {
        float val = bm[i] ? __expf(kin[(size_t)i * EE] - M) * inv : 0.f;
        kout[(size_t)i * DD] = __float2bfloat16(val);
    }
}

// ---------------------------------------------------------------------------
// Kernel 3: swapped-QK^T flash attention, 16x16x32 MFMA, fully-folded softmax:
// Q pre-scaled by K2C -> pv = exp2(S) plain; mask folded into V (zero cols);
// lsum computed by the MFMA via the ones-row tile O5. No mask arithmetic,
// no reduction tree in the loop. 16 q/wave, 4 waves, 1024 blocks.
// ---------------------------------------------------------------------------
__global__ __launch_bounds__(256) void attn_mfma_kernel(
    const __hip_bfloat16* __restrict__ qcb,
    const __hip_bfloat16* __restrict__ ksb,
    const __hip_bfloat16* __restrict__ vtb,
    float* __restrict__ out) {
    __shared__ __align__(16) short KsS[2][4096];   // 16 KB (64x64)
    __shared__ __align__(16) short VtS[2][5120];   // 20 KB (80x64)

    int tid = threadIdx.x;
    int lane = tid & 63;
    int w = tid >> 6;                  // 4 waves
    int q15 = lane & 15;
    int g = (lane >> 4) & 3;

    // XCD swizzle: 1024 blocks; 128 consecutive swz per XCD -> 8 bh per L2
    int bid = blockIdx.x;
    int swz = (bid & 7) * 128 + (bid >> 3);
    int bh = swz >> 4;
    int qb = swz & 15;
    int b = bh >> 4;
    int h = bh & 15;
    int q0w = qb * 64 + w * 16;

    // staging geometry: rows (tid>>3), 8 chunks of 8 bf16, XOR-swizzled source
    int srow = tid >> 3;
    int sch = tid & 7;
    int ssw = (sch ^ (srow & 7)) << 3;
    const short* kg = (const short*)ksb + (size_t)bh * LL * DD + (size_t)srow * DD + ssw;
    const short* vg = (const short*)vtb + (size_t)bh * VROWS * LL + (size_t)srow * LL + ssw;
    const short* vgx = (const short*)vtb + (size_t)bh * VROWS * LL + (size_t)(64 + srow) * LL + ssw;

    // Q fragments (pre-scaled by K2C)
    short8 Qf0, Qf1;
    {
        const short* qrow = (const short*)qcb + ((size_t)bh * LL + q0w + q15) * DD + 8 * g;
        Qf0 = *(const short8*)(qrow);
        Qf1 = *(const short8*)(qrow + 32);
    }

    // prologue: tile 0
    #pragma unroll
    for (int it = 0; it < 2; ++it) {
        __builtin_amdgcn_global_load_lds(
            (const __attribute__((address_space(1))) void*)(kg + (size_t)(it * 32) * DD),
            (__attribute__((address_space(3))) void*)&KsS[0][(it * 4 + w) * 512], 16, 0, 0);
        __builtin_amdgcn_global_load_lds(
            (const __attribute__((address_space(1))) void*)(vg + (size_t)it * 32 * LL),
            (__attribute__((address_space(3))) void*)&VtS[0][(it * 4 + w) * 512], 16, 0, 0);
    }
    if (w < 2) {
        __builtin_amdgcn_global_load_lds(
            (const __attribute__((address_space(1))) void*)(vgx),
            (__attribute__((address_space(3))) void*)&VtS[0][4096 + w * 512], 16, 0, 0);
    }

    f32x4 O[4], O5;
    #pragma unroll
    for (int u = 0; u < 4; ++u) O[u] = (f32x4){0.f, 0.f, 0.f, 0.f};
    O5 = (f32x4){0.f, 0.f, 0.f, 0.f};

    for (int kt = 0; kt < 16; ++kt) {
        __syncthreads();   // tile kt ready; all waves done with other slot

        if (kt < 15) {
            int nb = (kt + 1) & 1;
            int k0n = (kt + 1) * 64;
            #pragma unroll
            for (int it = 0; it < 2; ++it) {
                __builtin_amdgcn_global_load_lds(
                    (const __attribute__((address_space(1))) void*)(kg + (size_t)(k0n + it * 32) * DD),
                    (__attribute__((address_space(3))) void*)&KsS[nb][(it * 4 + w) * 512], 16, 0, 0);
                __builtin_amdgcn_global_load_lds(
                    (const __attribute__((address_space(1))) void*)(vg + k0n + (size_t)it * 32 * LL),
                    (__attribute__((address_space(3))) void*)&VtS[nb][(it * 4 + w) * 512], 16, 0, 0);
            }
            if (w < 2) {
                __builtin_amdgcn_global_load_lds(
                    (const __attribute__((address_space(1))) void*)(vgx + k0n),
                    (__attribute__((address_space(3))) void*)&VtS[nb][4096 + w * 512], 16, 0, 0);
            }
        }

        int cb = kt & 1;
        const short* Kb = KsS[cb];
        const short* Vb = VtS[cb];
        int sw = q15 & 7;
        int off0 = (g ^ sw) << 3;
        int off1 = ((g + 4) ^ sw) << 3;

        // S^T tiles: S[t] = K-subtile(16 kv) x Q  (K=64 via 2 mfma)
        f32x4 S[4];
        __builtin_amdgcn_s_setprio(1);
        #pragma unroll
        for (int t = 0; t < 4; ++t) {
            short8 kf0 = *(const short8*)&Kb[(16 * t + q15) * 64 + off0];
            short8 kf1 = *(const short8*)&Kb[(16 * t + q15) * 64 + off1];
            f32x4 z = (f32x4){0.f, 0.f, 0.f, 0.f};
            z = __builtin_amdgcn_mfma_f32_16x16x32_bf16(kf0, Qf0, z, 0, 0, 0);
            S[t] = __builtin_amdgcn_mfma_f32_16x16x32_bf16(kf1, Qf1, z, 0, 0, 0);
        }
        __builtin_amdgcn_s_setprio(0);

        // V fragments (issue early: LDS latency hides under exp2/pack)
        short8 vfa[5], vfb[5];
        #pragma unroll
        for (int u = 0; u < 5; ++u) {
            vfa[u] = *(const short8*)&Vb[(16 * u + q15) * 64 + off0];
            vfb[u] = *(const short8*)&Vb[(16 * u + q15) * 64 + off1];
        }

        // softmax: pv = exp2(S) — no bias, no mask (both folded away)
        float pv[4][4];
        #pragma unroll
        for (int t = 0; t < 4; ++t)
            #pragma unroll
            for (int r = 0; r < 4; ++r)
                pv[t][r] = exp2f(S[t][r]);

        // pack P -> lane-local B-fragments (permuted-V)
        int4v pa0, pa1;
        {
            int d0, d1, d2, d3;
            CVTPK(d0, pv[0][0], pv[0][1]);
            CVTPK(d1, pv[0][2], pv[0][3]);
            CVTPK(d2, pv[1][0], pv[1][1]);
            CVTPK(d3, pv[1][2], pv[1][3]);
            pa0 = (int4v){d0, d1, d2, d3};
            CVTPK(d0, pv[2][0], pv[2][1]);
            CVTPK(d1, pv[2][2], pv[2][3]);
            CVTPK(d2, pv[3][0], pv[3][1]);
            CVTPK(d3, pv[3][2], pv[3][3]);
            pa1 = (int4v){d0, d1, d2, d3};
        }
        union PW { int4v i4; short8 s8; } pw0, pw1;
        pw0.i4 = pa0;
        pw1.i4 = pa1;

        // O^T tiles + lsum tile O5 (ones-row x P)
        __builtin_amdgcn_s_setprio(1);
        #pragma unroll
        for (int u = 0; u < 4; ++u) {
            O[u] = __builtin_amdgcn_mfma_f32_16x16x32_bf16(vfa[u], pw0.s8, O[u], 0, 0, 0);
            O[u] = __builtin_amdgcn_mfma_f32_16x16x32_bf16(vfb[u], pw1.s8, O[u], 0, 0, 0);
        }
        O5 = __builtin_amdgcn_mfma_f32_16x16x32_bf16(vfa[4], pw0.s8, O5, 0, 0, 0);
        O5 = __builtin_amdgcn_mfma_f32_16x16x32_bf16(vfb[4], pw1.s8, O5, 0, 0, 0);
        __builtin_amdgcn_s_setprio(0);
    }

    // epilogue: lsum = O5 row 0 (lanes 0-15, reg 0), broadcast via shfl
    float ls = __shfl(O5[0], q15, 64);
    float invl = 1.f / ls;

    float* gout = out + ((size_t)b * LL + q0w + q15) * EE + h * DD + 4 * g;
    #pragma unroll
    for (int u = 0; u < 4; ++u) {
        float4 vv = { O[u][0] * invl, O[u][1] * invl, O[u][2] * invl, O[u][3] * invl };
        *(float4*)&gout[16 * u] = vv;
    }
}

extern "C" void kernel_launch(void* const* d_in, const int* in_sizes, int n_in,
                              void* d_out, int out_size, void* d_ws, size_t ws_size,
                              hipStream_t stream) {
    const float* query = (const float*)d_in[0];
    const float* keys  = (const float*)d_in[1];
    const float* values = (const float*)d_in[2];
    const int* pad  = (const int*)d_in[3];
    const int* cau  = (const int*)d_in[4];
    const int* bern = (const int*)d_in[5];
    const float* conv_w = (const float*)d_in[6];
    const float* conv_b = (const float*)d_in[7];
    const float* Wv = (const float*)d_in[8];
    float* outp = (float*)d_out;

    const size_t per = (size_t)BB * HH * LL * DD;      // 4,194,304
    const size_t vper = (size_t)BB * HH * VROWS * LL;  // 5,242,880
    __hip_bfloat16* qcb = (__hip_bfloat16*)d_ws;
    __hip_bfloat16* ksb = qcb + per;
    __hip_bfloat16* vtb = ksb + per;
    float* pmax = (float*)(vtb + vper);
    float* psum = pmax + (size_t)BB * HH * NCH * 64;

    prep_kernel<<<5632, 256, 0, stream>>>(query, conv_w, conv_b, values, Wv,
                                          keys, bern, pad, cau,
                                          qcb, vtb, pmax, psum);
    ksm_final_kernel<<<BB * HH * NCH, 256, 0, stream>>>(keys, bern, pmax, psum, ksb);
    attn_mfma_kernel<<<BB * HH * 16, 256, 0, stream>>>(qcb, ksb, vtb, outp);
}